// Round 1
// baseline (750.314 us; speedup 1.0000x reference)
//
#include <hip/hip_runtime.h>
#include <hip/hip_bf16.h>

typedef unsigned short u16;
typedef unsigned int   u32;
typedef __attribute__((ext_vector_type(4))) float  f32x4;
typedef __attribute__((ext_vector_type(8))) __bf16 bf16x8;

#define B_    4096
#define OBS_  512
#define DH_   1024
#define NEXP_ 8
#define DK_   256
#define DV_   1024

__device__ __forceinline__ float b2f(u32 lo16) {
  return __builtin_bit_cast(float, lo16 << 16);
}
__device__ __forceinline__ u16 f2b(float f) {   // RNE fp32 -> bf16
  u32 u = __builtin_bit_cast(u32, f);
  return (u16)((u + 0x7fffu + ((u >> 16) & 1u)) >> 16);
}

// ---------------- elementwise fp32 -> bf16 (x) ----------------
__global__ __launch_bounds__(256)
void conv_kernel(const float* __restrict__ in, u16* __restrict__ outp) {
  long i = ((long)blockIdx.x * 256 + threadIdx.x) * 4;
  float4 v = *(const float4*)(in + i);
  u16 o[4] = { f2b(v.x), f2b(v.y), f2b(v.z), f2b(v.w) };
  *(uint2*)(outp + i) = *(const uint2*)o;
}

// ---------------- batched transpose + convert: [z][R][C] f32 -> [z][C][R] bf16 ----------------
__global__ __launch_bounds__(256)
void tconv(const float* __restrict__ in, u16* __restrict__ outp, int R, int C) {
  __shared__ float tile[32][33];
  int z = blockIdx.z;
  in   += (long)z * R * C;
  outp += (long)z * R * C;
  int c0 = blockIdx.x * 32, r0 = blockIdx.y * 32;
  int tx = threadIdx.x, ty = threadIdx.y;   // (32, 8)
#pragma unroll
  for (int i = 0; i < 4; ++i)
    tile[ty + i * 8][tx] = in[(long)(r0 + ty + i * 8) * C + c0 + tx];
  __syncthreads();
#pragma unroll
  for (int i = 0; i < 4; ++i)
    outp[(long)(c0 + ty + i * 8) * R + r0 + tx] = f2b(tile[tx][ty + i * 8]);
}

// ---------------- q vector + c_n = bk[n]·q ----------------
__global__ __launch_bounds__(256)
void qcn_kernel(const float* __restrict__ Wq, const float* __restrict__ bq,
                const float* __restrict__ bk, const int* __restrict__ task,
                float* __restrict__ q, float* __restrict__ cn) {
  __shared__ float qs[DK_];
  int t = *task;
  int tid = threadIdx.x;
  float qv = Wq[(t * 10 + t) * DK_ + tid] + bq[t * DK_ + tid];
  q[tid] = qv;
  qs[tid] = qv;
  __syncthreads();
  if (tid < NEXP_) {
    float s = 0.f;
    for (int k = 0; k < DK_; ++k) s += bk[tid * DK_ + k] * qs[k];
    cn[tid] = s;
  }
}

// ---------------- w_nq[n][d] = Wk[n][d][:]·q  (one wave per row) ----------------
__global__ __launch_bounds__(256)
void wnq_kernel(const float* __restrict__ Wk, const float* __restrict__ q,
                float* __restrict__ wnq) {
  int row  = blockIdx.x * 4 + (threadIdx.x >> 6);   // 0..8191
  int lane = threadIdx.x & 63;
  const float* wr = Wk + (long)row * DK_;
  float s = 0.f;
#pragma unroll
  for (int i = 0; i < 4; ++i) s += wr[lane + i * 64] * q[lane + i * 64];
  for (int off = 32; off; off >>= 1) s += __shfl_xor(s, off);
  if (lane == 0) wnq[row] = s;
}

// ---------------- expkq[n][b] = e2[n][b][:]·w_nq[n] + c_n  (wave per row) ----------------
__global__ __launch_bounds__(256)
void expkq_kernel(const u16* __restrict__ e2, const float* __restrict__ wnq,
                  const float* __restrict__ cn, float* __restrict__ ekq) {
  int row  = blockIdx.x * 4 + (threadIdx.x >> 6);   // n*4096 + b
  int n    = row >> 12;
  int lane = threadIdx.x & 63;
  const u16*   er = e2 + (long)row * DH_;
  const float* w  = wnq + n * DH_;
  float s = 0.f;
#pragma unroll
  for (int i = 0; i < 8; ++i) {
    int j = lane + i * 64;                 // pair index, 512 pairs
    u32 p = *(const u32*)(er + 2 * j);
    float2 wv = *(const float2*)(w + 2 * j);
    s += b2f(p & 0xffffu) * wv.x + b2f(p >> 16) * wv.y;
  }
  for (int off = 32; off; off >>= 1) s += __shfl_xor(s, off);
  if (lane == 0) ekq[row] = s + cn[n];
}

// ---------------- scaled_e[b][n*DH+d] = bf16(expkq[n][b] * e2[n][b][d]) ----------------
__global__ __launch_bounds__(256)
void scalepack(const u16* __restrict__ e2, const float* __restrict__ ekq,
               u16* __restrict__ se) {
  long flat = (long)blockIdx.x * 256 + threadIdx.x;  // chunk of 8 bf16
  int d8 = flat & 127;
  int n  = (flat >> 7) & 7;
  int b  = (int)(flat >> 10);
  float s = ekq[n * B_ + b];
  uint4 v = *(const uint4*)(e2 + ((long)(n * B_ + b) * DH_) + d8 * 8);
  u32* vi = (u32*)&v;
  u16 o[8];
#pragma unroll
  for (int i = 0; i < 4; ++i) {
    u32 p = vi[i];
    o[2 * i]     = f2b(b2f(p & 0xffffu) * s);
    o[2 * i + 1] = f2b(b2f(p >> 16) * s);
  }
  *(uint4*)(se + (long)b * (NEXP_ * DH_) + n * DH_ + d8 * 8) = *(const uint4*)o;
}

// ---------------- generic MFMA GEMM: C = act(A[M,K] @ Bt[N,K]^T + bias) ----------------
// 128x128 tile, 4 waves (2x2), each wave 4x4 mfma_f32_16x16x32_bf16.
// LDS rows padded to 40 bf16 -> conflict-light ds_read_b128 fragments.
template<int RELU, int BF16OUT, int RESBIAS>
__global__ __launch_bounds__(256)
void gemm_bt(const u16* __restrict__ A, const u16* __restrict__ Bt,
             const float* __restrict__ bias, void* __restrict__ Cv,
             int M, int N, int K,
             long aB, long bB, long biasB, long cBbytes,
             const float* __restrict__ ekq, const float* __restrict__ bvp) {
  int z = blockIdx.z;
  A  += (long)z * aB;
  Bt += (long)z * bB;
  const float* bptr = bias ? bias + (long)z * biasB : nullptr;
  char* Cb = (char*)Cv + (long)z * cBbytes;

  const int m0 = blockIdx.y * 128, n0 = blockIdx.x * 128;
  __shared__ u16 As[128 * 40];
  __shared__ u16 Bs[128 * 40];
  const int tid  = threadIdx.x;
  const int lane = tid & 63, wid = tid >> 6;
  const int wm = (wid >> 1) * 64, wn = (wid & 1) * 64;
  const int lr = lane & 15, quad = lane >> 4;

  f32x4 acc[4][4] = {};

  for (int k0 = 0; k0 < K; k0 += 32) {
    __syncthreads();
#pragma unroll
    for (int s = 0; s < 2; ++s) {
      int flat = tid * 8 + s * 2048;     // 128x32 tile, 8 bf16 per chunk
      int r = flat >> 5, c = flat & 31;
      uint4 va = *(const uint4*)(A  + (long)(m0 + r) * K + k0 + c);
      *(uint4*)(&As[r * 40 + c]) = va;
      uint4 vb = *(const uint4*)(Bt + (long)(n0 + r) * K + k0 + c);
      *(uint4*)(&Bs[r * 40 + c]) = vb;
    }
    __syncthreads();
    bf16x8 af[4], bfr[4];
#pragma unroll
    for (int i = 0; i < 4; ++i)
      af[i]  = *(const bf16x8*)(&As[(wm + i * 16 + lr) * 40 + quad * 8]);
#pragma unroll
    for (int i = 0; i < 4; ++i)
      bfr[i] = *(const bf16x8*)(&Bs[(wn + i * 16 + lr) * 40 + quad * 8]);
#pragma unroll
    for (int mi = 0; mi < 4; ++mi)
#pragma unroll
      for (int ni = 0; ni < 4; ++ni)
        acc[mi][ni] = __builtin_amdgcn_mfma_f32_16x16x32_bf16(af[mi], bfr[ni], acc[mi][ni], 0, 0, 0);
  }

  // epilogue: C/D layout col=lane&15, row=quad*4+reg (verified m89/m91)
#pragma unroll
  for (int mi = 0; mi < 4; ++mi) {
#pragma unroll
    for (int ni = 0; ni < 4; ++ni) {
      int col = n0 + wn + ni * 16 + lr;
      float bcol = bptr ? bptr[col] : 0.f;
#pragma unroll
      for (int r = 0; r < 4; ++r) {
        int row = m0 + wm + mi * 16 + quad * 4 + r;
        float v = acc[mi][ni][r] + bcol;
        if (RESBIAS) {
#pragma unroll
          for (int n = 0; n < NEXP_; ++n)
            v += ekq[n * M + row] * bvp[n * N + col];
        }
        if (RELU) v = fmaxf(v, 0.f);
        if (BF16OUT) ((u16*)Cb)[(long)row * N + col] = f2b(v);
        else         ((float*)Cb)[(long)row * N + col] = v;
      }
    }
  }
}

// ---------------- split / clip / exp ----------------
__global__ __launch_bounds__(256)
void finalize(const float* __restrict__ of, float* __restrict__ outp) {
  int flat = blockIdx.x * 256 + threadIdx.x;   // 4096*128
  int c = flat & 127, b = flat >> 7;
  float v = of[flat];
  if (c < 64) {
    outp[b * 64 + c] = v;                                  // mean
  } else {
    int i = b * 64 + (c - 64);
    float ls = fminf(fmaxf(v, -20.f), 2.f);
    outp[262144 + i] = expf(ls);                           // std
    outp[524288 + i] = ls;                                 // log_std
  }
}

extern "C" void kernel_launch(void* const* d_in, const int* in_sizes, int n_in,
                              void* d_out, int out_size, void* d_ws, size_t ws_size,
                              hipStream_t stream) {
  const float* x   = (const float*)d_in[0];
  const int*   task= (const int*)  d_in[1];
  const float* Wb1 = (const float*)d_in[2];
  const float* bb1 = (const float*)d_in[3];
  const float* Wb2 = (const float*)d_in[4];
  const float* bb2 = (const float*)d_in[5];
  const float* We1 = (const float*)d_in[6];
  const float* be1 = (const float*)d_in[7];
  const float* We2 = (const float*)d_in[8];
  const float* be2 = (const float*)d_in[9];
  const float* Wv  = (const float*)d_in[10];
  const float* bv  = (const float*)d_in[11];
  const float* Wk  = (const float*)d_in[12];
  const float* bk  = (const float*)d_in[13];
  const float* Wq  = (const float*)d_in[14];
  const float* bq  = (const float*)d_in[15];
  const float* Wt1 = (const float*)d_in[16];
  const float* bt1 = (const float*)d_in[17];
  const float* Wl  = (const float*)d_in[18];
  const float* bl  = (const float*)d_in[19];
  float* outp = (float*)d_out;

  char* ws = (char*)d_ws;
  size_t off = 0;
  auto alloc = [&](size_t bytes) -> char* {
    char* p = ws + off;
    off += (bytes + 255) & ~(size_t)255;
    return p;
  };

  u16* xb    = (u16*)alloc((size_t)B_ * OBS_ * 2);
  u16* Wb1T  = (u16*)alloc((size_t)DH_ * OBS_ * 2);
  u16* Wb2T  = (u16*)alloc((size_t)DH_ * DH_ * 2);
  u16* We1T  = (u16*)alloc((size_t)NEXP_ * DH_ * DH_ * 2);
  u16* We2T  = (u16*)alloc((size_t)NEXP_ * DH_ * DH_ * 2);
  u16* WvT   = (u16*)alloc((size_t)DV_ * NEXP_ * DH_ * 2);   // [DV][N*DH]
  u16* Wt1T  = (u16*)alloc((size_t)DH_ * DV_ * 2);
  u16* WlT   = (u16*)alloc((size_t)128 * DH_ * 2);
  u16* h1    = (u16*)alloc((size_t)B_ * DH_ * 2);
  u16* h     = (u16*)alloc((size_t)B_ * DH_ * 2);
  u16* e1    = (u16*)alloc((size_t)NEXP_ * B_ * DH_ * 2);
  u16* e2    = (u16*)alloc((size_t)NEXP_ * B_ * DH_ * 2);
  float* qv  = (float*)alloc(DK_ * 4);
  float* cn  = (float*)alloc(NEXP_ * 4);
  float* wnq = (float*)alloc((size_t)NEXP_ * DH_ * 4);
  float* ekq = (float*)alloc((size_t)NEXP_ * B_ * 4);
  float* outfull = (float*)alloc((size_t)B_ * 128 * 4);
  // buffer reuse (dead after their consumer GEMM):
  u16* se  = e1;   // scaled_e [B][N*DH]
  u16* res = h1;   // res      [B][DV]
  u16* tt  = h;    // t        [B][DH]

  dim3 tb(32, 8);
  // converts / transposes
  conv_kernel<<<(B_ * OBS_) / 1024, 256, 0, stream>>>(x, xb);
  tconv<<<dim3(32, 16, 1),  tb, 0, stream>>>(Wb1, Wb1T, OBS_, DH_);
  tconv<<<dim3(32, 32, 1),  tb, 0, stream>>>(Wb2, Wb2T, DH_, DH_);
  tconv<<<dim3(32, 32, 8),  tb, 0, stream>>>(We1, We1T, DH_, DH_);
  tconv<<<dim3(32, 32, 8),  tb, 0, stream>>>(We2, We2T, DH_, DH_);
  tconv<<<dim3(32, 256, 1), tb, 0, stream>>>(Wv, WvT, NEXP_ * DH_, DV_);
  tconv<<<dim3(32, 32, 1),  tb, 0, stream>>>(Wt1, Wt1T, DV_, DH_);
  tconv<<<dim3(4, 32, 1),   tb, 0, stream>>>(Wl, WlT, DH_, 128);
  // q / c_n / w_nq
  qcn_kernel<<<1, 256, 0, stream>>>(Wq, bq, bk, task, qv, cn);
  wnq_kernel<<<(NEXP_ * DH_) / 4, 256, 0, stream>>>(Wk, qv, wnq);
  // base MLP
  gemm_bt<1, 1, 0><<<dim3(8, 32, 1), 256, 0, stream>>>(xb, Wb1T, bb1, h1,
      B_, DH_, OBS_, 0, 0, 0, 0, nullptr, nullptr);
  gemm_bt<1, 1, 0><<<dim3(8, 32, 1), 256, 0, stream>>>(h1, Wb2T, bb2, h,
      B_, DH_, DH_, 0, 0, 0, 0, nullptr, nullptr);
  // experts (batched over z)
  gemm_bt<1, 1, 0><<<dim3(8, 32, 8), 256, 0, stream>>>(h, We1T, be1, e1,
      B_, DH_, DH_, 0, (long)DH_ * DH_, DH_, (long)B_ * DH_ * 2, nullptr, nullptr);
  gemm_bt<1, 1, 0><<<dim3(8, 32, 8), 256, 0, stream>>>(e1, We2T, be2, e2,
      B_, DH_, DH_, (long)B_ * DH_, (long)DH_ * DH_, DH_, (long)B_ * DH_ * 2, nullptr, nullptr);
  // attention weights + scaling
  expkq_kernel<<<(NEXP_ * B_) / 4, 256, 0, stream>>>(e2, wnq, cn, ekq);
  scalepack<<<(long)NEXP_ * B_ * DH_ / 8 / 256, 256, 0, stream>>>(e2, ekq, se);
  // res = scaled_e @ Wv_flat + sum_n ekq*bv   (K = 8192)
  gemm_bt<0, 1, 1><<<dim3(8, 32, 1), 256, 0, stream>>>(se, WvT, nullptr, res,
      B_, DV_, NEXP_ * DH_, 0, 0, 0, 0, ekq, bv);
  // tower + last
  gemm_bt<1, 1, 0><<<dim3(8, 32, 1), 256, 0, stream>>>(res, Wt1T, bt1, tt,
      B_, DH_, DV_, 0, 0, 0, 0, nullptr, nullptr);
  gemm_bt<0, 0, 0><<<dim3(1, 32, 1), 256, 0, stream>>>(tt, WlT, bl, outfull,
      B_, 128, DH_, 0, 0, 0, 0, nullptr, nullptr);
  finalize<<<(B_ * 128) / 256, 256, 0, stream>>>(outfull, outp);
}

// Round 2
// 656.359 us; speedup vs baseline: 1.1431x; 1.1431x over previous
//
#include <hip/hip_runtime.h>
#include <hip/hip_bf16.h>

typedef unsigned short u16;
typedef unsigned int   u32;
typedef __attribute__((ext_vector_type(4))) float  f32x4;
typedef __attribute__((ext_vector_type(8))) __bf16 bf16x8;

#define B_    4096
#define OBS_  512
#define DH_   1024
#define NEXP_ 8
#define DK_   256
#define DV_   1024

__device__ __forceinline__ float b2f(u32 lo16) {
  return __builtin_bit_cast(float, lo16 << 16);
}
__device__ __forceinline__ u16 f2b(float f) {   // RNE fp32 -> bf16
  u32 u = __builtin_bit_cast(u32, f);
  return (u16)((u + 0x7fffu + ((u >> 16) & 1u)) >> 16);
}
// async global->LDS, 16 B per lane; LDS dest = wave-uniform base + lane*16
__device__ __forceinline__ void gl_lds16(const u16* g, u16* l) {
  __builtin_amdgcn_global_load_lds(
      (__attribute__((address_space(1))) void*)(void*)g,
      (__attribute__((address_space(3))) void*)(void*)l,
      16, 0, 0);
}

// ---------------- elementwise fp32 -> bf16 (x) ----------------
__global__ __launch_bounds__(256)
void conv_kernel(const float* __restrict__ in, u16* __restrict__ outp) {
  long i = ((long)blockIdx.x * 256 + threadIdx.x) * 4;
  float4 v = *(const float4*)(in + i);
  u16 o[4] = { f2b(v.x), f2b(v.y), f2b(v.z), f2b(v.w) };
  *(uint2*)(outp + i) = *(const uint2*)o;
}

// ---------------- batched transpose + convert: [z][R][C] f32 -> [z][C][R] bf16 ----------------
__global__ __launch_bounds__(256)
void tconv(const float* __restrict__ in, u16* __restrict__ outp, int R, int C) {
  __shared__ float tile[32][33];
  int z = blockIdx.z;
  in   += (long)z * R * C;
  outp += (long)z * R * C;
  int c0 = blockIdx.x * 32, r0 = blockIdx.y * 32;
  int tx = threadIdx.x, ty = threadIdx.y;   // (32, 8)
#pragma unroll
  for (int i = 0; i < 4; ++i)
    tile[ty + i * 8][tx] = in[(long)(r0 + ty + i * 8) * C + c0 + tx];
  __syncthreads();
#pragma unroll
  for (int i = 0; i < 4; ++i)
    outp[(long)(c0 + ty + i * 8) * R + r0 + tx] = f2b(tile[tx][ty + i * 8]);
}

// ---------------- q vector + c_n = bk[n]·q ----------------
__global__ __launch_bounds__(256)
void qcn_kernel(const float* __restrict__ Wq, const float* __restrict__ bq,
                const float* __restrict__ bk, const int* __restrict__ task,
                float* __restrict__ q, float* __restrict__ cn) {
  __shared__ float qs[DK_];
  int t = *task;
  int tid = threadIdx.x;
  float qv = Wq[(t * 10 + t) * DK_ + tid] + bq[t * DK_ + tid];
  q[tid] = qv;
  qs[tid] = qv;
  __syncthreads();
  if (tid < NEXP_) {
    float s = 0.f;
    for (int k = 0; k < DK_; ++k) s += bk[tid * DK_ + k] * qs[k];
    cn[tid] = s;
  }
}

// ---------------- w_nq[n][d] = Wk[n][d][:]·q  (one wave per row) ----------------
__global__ __launch_bounds__(256)
void wnq_kernel(const float* __restrict__ Wk, const float* __restrict__ q,
                float* __restrict__ wnq) {
  int row  = blockIdx.x * 4 + (threadIdx.x >> 6);   // 0..8191
  int lane = threadIdx.x & 63;
  const float* wr = Wk + (long)row * DK_;
  float s = 0.f;
#pragma unroll
  for (int i = 0; i < 4; ++i) s += wr[lane + i * 64] * q[lane + i * 64];
  for (int off = 32; off; off >>= 1) s += __shfl_xor(s, off);
  if (lane == 0) wnq[row] = s;
}

// ---- fused: expkq[n][b] = e2 row · wnq[n] + c_n ; se[b][n*DH+d] = bf16(expkq * e2) ----
// one wave per (n,b) row; each lane owns 16 contiguous elements.
__global__ __launch_bounds__(256)
void ekqscale(const u16* __restrict__ e2, const float* __restrict__ wnq,
              const float* __restrict__ cn, float* __restrict__ ekq,
              u16* __restrict__ se) {
  int row  = blockIdx.x * 4 + (threadIdx.x >> 6);   // n*4096 + b
  int n    = row >> 12, b = row & (B_ - 1);
  int lane = threadIdx.x & 63;
  const u16*   er = e2 + (long)row * DH_ + lane * 16;
  const float* w  = wnq + n * DH_ + lane * 16;
  uint4 p0 = *(const uint4*)er;
  uint4 p1 = *(const uint4*)(er + 8);
  float4 w0 = *(const float4*)(w);
  float4 w1 = *(const float4*)(w + 4);
  float4 w2 = *(const float4*)(w + 8);
  float4 w3 = *(const float4*)(w + 12);
  const u32* pi = (const u32*)&p0;   // p0,p1 adjacent on stack? keep separate:
  float e[16];
  {
    const u32* a = (const u32*)&p0;
    const u32* c = (const u32*)&p1;
#pragma unroll
    for (int i = 0; i < 4; ++i) {
      e[2 * i]     = b2f(a[i] & 0xffffu);
      e[2 * i + 1] = b2f(a[i] >> 16);
      e[8 + 2 * i]     = b2f(c[i] & 0xffffu);
      e[8 + 2 * i + 1] = b2f(c[i] >> 16);
    }
  }
  (void)pi;
  const float* wf = (const float*)&w0;  // w0..w3 not contiguous; do explicit dot
  (void)wf;
  float s = e[0]*w0.x + e[1]*w0.y + e[2]*w0.z + e[3]*w0.w
          + e[4]*w1.x + e[5]*w1.y + e[6]*w1.z + e[7]*w1.w
          + e[8]*w2.x + e[9]*w2.y + e[10]*w2.z + e[11]*w2.w
          + e[12]*w3.x + e[13]*w3.y + e[14]*w3.z + e[15]*w3.w;
  for (int off = 32; off; off >>= 1) s += __shfl_xor(s, off);
  s += cn[n];
  if (lane == 0) ekq[row] = s;
  u16 o[16];
#pragma unroll
  for (int i = 0; i < 16; ++i) o[i] = f2b(e[i] * s);
  u16* dst = se + (long)b * (NEXP_ * DH_) + n * DH_ + lane * 16;
  *(uint4*)dst       = *(const uint4*)(o);
  *(uint4*)(dst + 8) = *(const uint4*)(o + 8);
}

// ---------------- MFMA GEMM, m97 staging: C = A[M,K] @ Bt[N,K]^T ----------------
// 128x128 tile, 4 waves (2x2), 4x4 mfma_f32_16x16x32_bf16 per wave.
// LDS stride 32 (no pad) — required by global_load_lds lane->dest mapping.
// OUT==0: bf16 out with bias+optional relu. OUT==1: fp32 partial (split-K), no bias.
template<int RELU, int OUT>
__global__ __launch_bounds__(256)
void gemm_bt(const u16* __restrict__ A, const u16* __restrict__ Bt,
             const float* __restrict__ bias, void* __restrict__ Cv,
             int M, int N, int kper, int lda, int ldb, int ksplit,
             long aB, long bB, long biasB, long cB) {
  const int zz = blockIdx.z;
  const int split = zz % ksplit;
  const int batch = zz / ksplit;
  A  += (long)batch * aB + (long)split * kper;
  Bt += (long)batch * bB + (long)split * kper;

  const int m0 = blockIdx.y * 128, n0 = blockIdx.x * 128;
  __shared__ u16 As[128 * 32];
  __shared__ u16 Bs[128 * 32];
  const int tid  = threadIdx.x;
  const int lane = tid & 63, wid = tid >> 6;
  const int wm = (wid >> 1) * 64, wn = (wid & 1) * 64;
  const int lr = lane & 15, quad = lane >> 4;
  const int srow = lane >> 2, scol = (lane & 3) * 8;

  // staging pointers: wave wid covers rows [wid*32, wid*32+32) of each slab
  const u16* a0 = A  + (long)(m0 + wid * 32 + srow) * lda + scol;
  const u16* a1 = a0 + (long)16 * lda;
  const u16* b0 = Bt + (long)(n0 + wid * 32 + srow) * ldb + scol;
  const u16* b1 = b0 + (long)16 * ldb;
  u16* la0 = &As[wid * 1024];
  u16* la1 = &As[wid * 1024 + 512];
  u16* lb0 = &Bs[wid * 1024];
  u16* lb1 = &Bs[wid * 1024 + 512];

  f32x4 acc[4][4] = {};

  for (int k0 = 0; k0 < kper; k0 += 32) {
    __syncthreads();
    gl_lds16(a0, la0); gl_lds16(a1, la1);
    gl_lds16(b0, lb0); gl_lds16(b1, lb1);
    a0 += 32; a1 += 32; b0 += 32; b1 += 32;
    __syncthreads();
    bf16x8 af[4], bfr[4];
#pragma unroll
    for (int i = 0; i < 4; ++i)
      af[i]  = *(const bf16x8*)(&As[(wm + i * 16 + lr) * 32 + quad * 8]);
#pragma unroll
    for (int i = 0; i < 4; ++i)
      bfr[i] = *(const bf16x8*)(&Bs[(wn + i * 16 + lr) * 32 + quad * 8]);
#pragma unroll
    for (int mi = 0; mi < 4; ++mi)
#pragma unroll
      for (int ni = 0; ni < 4; ++ni)
        acc[mi][ni] = __builtin_amdgcn_mfma_f32_16x16x32_bf16(af[mi], bfr[ni], acc[mi][ni], 0, 0, 0);
  }

  // epilogue: C/D layout col=lane&15, row=quad*4+reg (verified m89/m91)
  if (OUT == 1) {
    float* C = (float*)Cv + (long)split * ((long)M * N);
#pragma unroll
    for (int mi = 0; mi < 4; ++mi)
#pragma unroll
      for (int ni = 0; ni < 4; ++ni) {
        int col = n0 + wn + ni * 16 + lr;
#pragma unroll
        for (int r = 0; r < 4; ++r) {
          int row = m0 + wm + mi * 16 + quad * 4 + r;
          C[(long)row * N + col] = acc[mi][ni][r];
        }
      }
  } else {
    u16* C = (u16*)Cv + (long)batch * cB;
    const float* bptr = bias + (long)batch * biasB;
#pragma unroll
    for (int mi = 0; mi < 4; ++mi)
#pragma unroll
      for (int ni = 0; ni < 4; ++ni) {
        int col = n0 + wn + ni * 16 + lr;
        float bcol = bptr[col];
#pragma unroll
        for (int r = 0; r < 4; ++r) {
          int row = m0 + wm + mi * 16 + quad * 4 + r;
          float v = acc[mi][ni][r] + bcol;
          if (RELU) v = fmaxf(v, 0.f);
          C[(long)row * N + col] = f2b(v);
        }
      }
  }
}

// ---------------- reduce 2 fp32 partials + bias + relu -> bf16 ----------------
__global__ __launch_bounds__(256)
void reduce2_relu(const float* __restrict__ part, const float* __restrict__ bias,
                  u16* __restrict__ outp, int N, long stride) {
  long f4 = ((long)blockIdx.x * 256 + threadIdx.x) * 4;
  float4 v0 = *(const float4*)(part + f4);
  float4 v1 = *(const float4*)(part + stride + f4);
  int col = (int)(f4 % N);
  float4 bb = *(const float4*)(bias + col);
  u16 o[4];
  o[0] = f2b(fmaxf(v0.x + v1.x + bb.x, 0.f));
  o[1] = f2b(fmaxf(v0.y + v1.y + bb.y, 0.f));
  o[2] = f2b(fmaxf(v0.z + v1.z + bb.z, 0.f));
  o[3] = f2b(fmaxf(v0.w + v1.w + bb.w, 0.f));
  *(uint2*)(outp + f4) = *(const uint2*)o;
}

// ------------- reduce 4 fp32 partials + sum_n ekq[n,b]*bv[n,v] -> bf16 res -------------
__global__ __launch_bounds__(256)
void reduce4_res(const float* __restrict__ part, const float* __restrict__ ekq,
                 const float* __restrict__ bv, u16* __restrict__ outp) {
  long f4 = ((long)blockIdx.x * 256 + threadIdx.x) * 4;   // over B_*DV_
  int b = (int)(f4 >> 10);
  int v = (int)(f4 & (DV_ - 1));
  const long S = (long)B_ * DV_;
  float4 a0 = *(const float4*)(part + f4);
  float4 a1 = *(const float4*)(part + S + f4);
  float4 a2 = *(const float4*)(part + 2 * S + f4);
  float4 a3 = *(const float4*)(part + 3 * S + f4);
  float ax = a0.x + a1.x + a2.x + a3.x;
  float ay = a0.y + a1.y + a2.y + a3.y;
  float az = a0.z + a1.z + a2.z + a3.z;
  float aw = a0.w + a1.w + a2.w + a3.w;
#pragma unroll
  for (int n = 0; n < NEXP_; ++n) {
    float s = ekq[n * B_ + b];
    float4 bb = *(const float4*)(bv + n * DV_ + v);
    ax += s * bb.x; ay += s * bb.y; az += s * bb.z; aw += s * bb.w;
  }
  u16 o[4] = { f2b(ax), f2b(ay), f2b(az), f2b(aw) };
  *(uint2*)(outp + f4) = *(const uint2*)o;
}

// ---------------- reduce 8 Wl partials + bl, then split/clip/exp ----------------
__global__ __launch_bounds__(256)
void reduce_final(const float* __restrict__ part, const float* __restrict__ bl,
                  float* __restrict__ outp) {
  int flat = blockIdx.x * 256 + threadIdx.x;   // 4096*128
  int c = flat & 127, b = flat >> 7;
  float v = bl[c];
  const long S = (long)B_ * 128;
#pragma unroll
  for (int s = 0; s < 8; ++s) v += part[s * S + flat];
  if (c < 64) {
    outp[b * 64 + c] = v;                                  // mean
  } else {
    int i = b * 64 + (c - 64);
    float ls = fminf(fmaxf(v, -20.f), 2.f);
    outp[262144 + i] = expf(ls);                           // std
    outp[524288 + i] = ls;                                 // log_std
  }
}

extern "C" void kernel_launch(void* const* d_in, const int* in_sizes, int n_in,
                              void* d_out, int out_size, void* d_ws, size_t ws_size,
                              hipStream_t stream) {
  const float* x   = (const float*)d_in[0];
  const int*   task= (const int*)  d_in[1];
  const float* Wb1 = (const float*)d_in[2];
  const float* bb1 = (const float*)d_in[3];
  const float* Wb2 = (const float*)d_in[4];
  const float* bb2 = (const float*)d_in[5];
  const float* We1 = (const float*)d_in[6];
  const float* be1 = (const float*)d_in[7];
  const float* We2 = (const float*)d_in[8];
  const float* be2 = (const float*)d_in[9];
  const float* Wv  = (const float*)d_in[10];
  const float* bv  = (const float*)d_in[11];
  const float* Wk  = (const float*)d_in[12];
  const float* bk  = (const float*)d_in[13];
  const float* Wq  = (const float*)d_in[14];
  const float* bq  = (const float*)d_in[15];
  const float* Wt1 = (const float*)d_in[16];
  const float* bt1 = (const float*)d_in[17];
  const float* Wl  = (const float*)d_in[18];
  const float* bl  = (const float*)d_in[19];
  float* outp = (float*)d_out;

  char* ws = (char*)d_ws;
  size_t off = 0;
  auto alloc = [&](size_t bytes) -> char* {
    char* p = ws + off;
    off += (bytes + 255) & ~(size_t)255;
    return p;
  };

  u16* xb    = (u16*)alloc((size_t)B_ * OBS_ * 2);
  u16* Wb1T  = (u16*)alloc((size_t)DH_ * OBS_ * 2);
  u16* Wb2T  = (u16*)alloc((size_t)DH_ * DH_ * 2);
  u16* We1T  = (u16*)alloc((size_t)NEXP_ * DH_ * DH_ * 2);
  u16* We2T  = (u16*)alloc((size_t)NEXP_ * DH_ * DH_ * 2);
  u16* WvT   = (u16*)alloc((size_t)DV_ * NEXP_ * DH_ * 2);   // [DV][N*DH]
  u16* Wt1T  = (u16*)alloc((size_t)DH_ * DV_ * 2);
  u16* WlT   = (u16*)alloc((size_t)128 * DH_ * 2);
  u16* h1    = (u16*)alloc((size_t)B_ * DH_ * 2);
  u16* h     = (u16*)alloc((size_t)B_ * DH_ * 2);
  u16* e1    = (u16*)alloc((size_t)NEXP_ * B_ * DH_ * 2);    // 64 MB region
  u16* e2    = (u16*)alloc((size_t)NEXP_ * B_ * DH_ * 2);    // 64 MB region
  float* qv  = (float*)alloc(DK_ * 4);
  float* cn  = (float*)alloc(NEXP_ * 4);
  float* wnq = (float*)alloc((size_t)NEXP_ * DH_ * 4);
  float* ekq = (float*)alloc((size_t)NEXP_ * B_ * 4);
  // buffer reuse (regions dead by the time they're re-purposed):
  u16*   se     = e1;            // scaled_e [B][N*DH]  (e1 dead after e2 GEMM)
  u16*   res    = h1;            // res      [B][DV]    (h1 dead after h GEMM)
  u16*   tt     = h;             // t        [B][DH]    (h dead after e1 GEMM... reused post-res)
  float* partE1 = (float*)e1;    // split-K partials for h1/h/Wt1/Wl (<=32 MB)
  float* partE2 = (float*)e2;    // split-K partials for res (64 MB, e2 dead after ekqscale)

  dim3 tb(32, 8);
  // converts / transposes
  conv_kernel<<<(B_ * OBS_) / 1024, 256, 0, stream>>>(x, xb);
  tconv<<<dim3(32, 16, 1),  tb, 0, stream>>>(Wb1, Wb1T, OBS_, DH_);
  tconv<<<dim3(32, 32, 1),  tb, 0, stream>>>(Wb2, Wb2T, DH_, DH_);
  tconv<<<dim3(32, 32, 8),  tb, 0, stream>>>(We1, We1T, DH_, DH_);
  tconv<<<dim3(32, 32, 8),  tb, 0, stream>>>(We2, We2T, DH_, DH_);
  tconv<<<dim3(32, 256, 1), tb, 0, stream>>>(Wv, WvT, NEXP_ * DH_, DV_);
  tconv<<<dim3(32, 32, 1),  tb, 0, stream>>>(Wt1, Wt1T, DV_, DH_);
  tconv<<<dim3(4, 32, 1),   tb, 0, stream>>>(Wl, WlT, DH_, 128);
  // q / c_n / w_nq
  qcn_kernel<<<1, 256, 0, stream>>>(Wq, bq, bk, task, qv, cn);
  wnq_kernel<<<(NEXP_ * DH_) / 4, 256, 0, stream>>>(Wk, qv, wnq);

  const long S1 = (long)B_ * DH_;   // partial stride (elems)
  // base MLP: h1 = relu(x@Wb1+bb1)   [split-K 2]
  gemm_bt<0, 1><<<dim3(8, 32, 2), 256, 0, stream>>>(xb, Wb1T, nullptr, partE1,
      B_, DH_, 256, OBS_, OBS_, 2, 0, 0, 0, 0);
  reduce2_relu<<<4096, 256, 0, stream>>>(partE1, bb1, h1, DH_, S1);
  // h = relu(h1@Wb2+bb2)   [split-K 2]
  gemm_bt<0, 1><<<dim3(8, 32, 2), 256, 0, stream>>>(h1, Wb2T, nullptr, partE1,
      B_, DH_, 512, DH_, DH_, 2, 0, 0, 0, 0);
  reduce2_relu<<<4096, 256, 0, stream>>>(partE1, bb2, h, DH_, S1);
  // experts (batched over z, no split)
  gemm_bt<1, 0><<<dim3(8, 32, 8), 256, 0, stream>>>(h, We1T, be1, e1,
      B_, DH_, DH_, DH_, DH_, 1, 0, (long)DH_ * DH_, DH_, (long)B_ * DH_);
  gemm_bt<1, 0><<<dim3(8, 32, 8), 256, 0, stream>>>(e1, We2T, be2, e2,
      B_, DH_, DH_, DH_, DH_, 1, (long)B_ * DH_, (long)DH_ * DH_, DH_, (long)B_ * DH_);
  // fused attention weights + scaling (reads e2 once)
  ekqscale<<<(NEXP_ * B_) / 4, 256, 0, stream>>>(e2, wnq, cn, ekq, se);
  // res = scaled_e @ Wv_flat  (K=8192, split-K 4 -> partials in e2 region)
  gemm_bt<0, 1><<<dim3(8, 32, 4), 256, 0, stream>>>(se, WvT, nullptr, partE2,
      B_, DV_, 2048, NEXP_ * DH_, NEXP_ * DH_, 4, 0, 0, 0, 0);
  reduce4_res<<<4096, 256, 0, stream>>>(partE2, ekq, bv, res);
  // tower: t = relu(res@Wt1+bt1)   [split-K 2, partials in e1 region]
  gemm_bt<0, 1><<<dim3(8, 32, 2), 256, 0, stream>>>(res, Wt1T, nullptr, partE1,
      B_, DH_, 512, DV_, DV_, 2, 0, 0, 0, 0);
  reduce2_relu<<<4096, 256, 0, stream>>>(partE1, bt1, tt, DH_, S1);
  // last: out = t@Wl+bl   [split-K 8, N=128]
  gemm_bt<0, 1><<<dim3(1, 32, 8), 256, 0, stream>>>(tt, WlT, nullptr, partE1,
      B_, 128, 128, DH_, DH_, 8, 0, 0, 0, 0);
  reduce_final<<<(B_ * 128) / 256, 256, 0, stream>>>(partE1, bl, outp);
}

// Round 3
// 595.834 us; speedup vs baseline: 1.2593x; 1.1016x over previous
//
#include <hip/hip_runtime.h>
#include <hip/hip_bf16.h>

typedef unsigned short u16;
typedef unsigned int   u32;
typedef __attribute__((ext_vector_type(4))) float  f32x4;
typedef __attribute__((ext_vector_type(8))) __bf16 bf16x8;

#define B_    4096
#define OBS_  512
#define DH_   1024
#define NEXP_ 8
#define DK_   256
#define DV_   1024

__device__ __forceinline__ float b2f(u32 lo16) {
  return __builtin_bit_cast(float, lo16 << 16);
}
__device__ __forceinline__ u16 f2b(float f) {   // RNE fp32 -> bf16
  u32 u = __builtin_bit_cast(u32, f);
  return (u16)((u + 0x7fffu + ((u >> 16) & 1u)) >> 16);
}
// async global->LDS, 16 B per lane; LDS dest = wave-uniform base + lane*16
__device__ __forceinline__ void gl_lds16(const u16* g, u16* l) {
  __builtin_amdgcn_global_load_lds(
      (__attribute__((address_space(1))) void*)(void*)g,
      (__attribute__((address_space(3))) void*)(void*)l,
      16, 0, 0);
}

// ---------------- merged prologue: fp32->bf16 convert of x + 7 weight transposes ----------------
// segments (flat blockIdx.x):
//   [0, 2048)              conv x          (2048 blocks, 1024 elems each)
//   [2048, +512)           Wb1  512x1024 -> T
//   [+512, +1024)          Wb2  1024x1024
//   [+1024, +8192)         We1  8 x 1024x1024 (per-z transpose)
//   [+8192, +8192)         We2  8 x 1024x1024
//   [+8192, +8192)         Wv   8192x1024 (flat transpose -> [DV][N*DH])
//   [+8192, +1024)         Wt1  1024x1024
//   [+1024, +128)          Wl   1024x128
__device__ __forceinline__ void tconv_body(const float* __restrict__ in,
                                           u16* __restrict__ outp,
                                           int R, int C, int rem, int tid) {
  __shared__ float tile[32][33];
  int gxs = (C == 128) ? 2 : 5;            // log2(C/32)
  int c0 = (rem & ((1 << gxs) - 1)) * 32;
  int r0 = (rem >> gxs) * 32;
  int tx = tid & 31, ty = tid >> 5;        // (32, 8)
#pragma unroll
  for (int i = 0; i < 4; ++i)
    tile[ty + i * 8][tx] = in[(long)(r0 + ty + i * 8) * C + c0 + tx];
  __syncthreads();
#pragma unroll
  for (int i = 0; i < 4; ++i)
    outp[(long)(c0 + ty + i * 8) * R + r0 + tx] = f2b(tile[tx][ty + i * 8]);
}

__global__ __launch_bounds__(256)
void prep(const float* __restrict__ x,  u16* __restrict__ xb,
          const float* __restrict__ Wb1, u16* __restrict__ Wb1T,
          const float* __restrict__ Wb2, u16* __restrict__ Wb2T,
          const float* __restrict__ We1, u16* __restrict__ We1T,
          const float* __restrict__ We2, u16* __restrict__ We2T,
          const float* __restrict__ Wv,  u16* __restrict__ WvT,
          const float* __restrict__ Wt1, u16* __restrict__ Wt1T,
          const float* __restrict__ Wl,  u16* __restrict__ WlT) {
  int tid = threadIdx.x;
  int bid = blockIdx.x;
  if (bid < 2048) {                         // conv x
    long i = ((long)bid * 256 + tid) * 4;
    float4 v = *(const float4*)(x + i);
    u16 o[4] = { f2b(v.x), f2b(v.y), f2b(v.z), f2b(v.w) };
    *(uint2*)(xb + i) = *(const uint2*)o;
    return;
  }
  bid -= 2048;
  if (bid < 512)  { tconv_body(Wb1, Wb1T, 512, 1024, bid, tid); return; }
  bid -= 512;
  if (bid < 1024) { tconv_body(Wb2, Wb2T, 1024, 1024, bid, tid); return; }
  bid -= 1024;
  if (bid < 8192) {
    int z = bid >> 10, rem = bid & 1023;
    tconv_body(We1 + (long)z * DH_ * DH_, We1T + (long)z * DH_ * DH_, 1024, 1024, rem, tid);
    return;
  }
  bid -= 8192;
  if (bid < 8192) {
    int z = bid >> 10, rem = bid & 1023;
    tconv_body(We2 + (long)z * DH_ * DH_, We2T + (long)z * DH_ * DH_, 1024, 1024, rem, tid);
    return;
  }
  bid -= 8192;
  if (bid < 8192) { tconv_body(Wv, WvT, 8192, 1024, bid, tid); return; }
  bid -= 8192;
  if (bid < 1024) { tconv_body(Wt1, Wt1T, 1024, 1024, bid, tid); return; }
  bid -= 1024;
  tconv_body(Wl, WlT, 1024, 128, bid, tid);
}

// ---------------- wnq[n][d] = Wk[n][d][:]·q ; block 2048 computes cn[n] = bk[n]·q ----------------
// q recomputed inline: q[j] = Wq[tid(task)] + bq (one-hot row select)
__global__ __launch_bounds__(256)
void wnq_cn(const float* __restrict__ Wq, const float* __restrict__ bq,
            const float* __restrict__ bk, const int* __restrict__ task,
            const float* __restrict__ Wk, float* __restrict__ wnq,
            float* __restrict__ cn) {
  int t = *task;
  const float* qrow = Wq + (long)(t * 10 + t) * DK_;
  const float* brow = bq + (long)t * DK_;
  int lane = threadIdx.x & 63;
  int bid = blockIdx.x;
  if (bid < 2048) {
    int row = bid * 4 + (threadIdx.x >> 6);   // 0..8191
    const float* wr = Wk + (long)row * DK_;
    float s = 0.f;
#pragma unroll
    for (int i = 0; i < 4; ++i) {
      int j = lane + i * 64;
      s += wr[j] * (qrow[j] + brow[j]);
    }
    for (int off = 32; off; off >>= 1) s += __shfl_xor(s, off);
    if (lane == 0) wnq[row] = s;
  } else {
    int w = threadIdx.x >> 6;
    for (int n = w; n < NEXP_; n += 4) {
      float s = 0.f;
#pragma unroll
      for (int i = 0; i < 4; ++i) {
        int j = lane + i * 64;
        s += bk[n * DK_ + j] * (qrow[j] + brow[j]);
      }
      for (int off = 32; off; off >>= 1) s += __shfl_xor(s, off);
      if (lane == 0) cn[n] = s;
    }
  }
}

// ---------------- expkq[n][b] = e2 row · wnq[n] + c_n  (one wave per row) ----------------
__global__ __launch_bounds__(256)
void expkq_k(const u16* __restrict__ e2, const float* __restrict__ wnq,
             const float* __restrict__ cn, float* __restrict__ ekq) {
  int row  = blockIdx.x * 4 + (threadIdx.x >> 6);   // n*4096 + b
  int n    = row >> 12;
  int lane = threadIdx.x & 63;
  const u16*   er = e2 + (long)row * DH_ + lane * 16;
  const float* w  = wnq + n * DH_ + lane * 16;
  uint4 p0 = *(const uint4*)er;
  uint4 p1 = *(const uint4*)(er + 8);
  float s = 0.f;
  const u32* a = (const u32*)&p0;
  const u32* c = (const u32*)&p1;
#pragma unroll
  for (int i = 0; i < 4; ++i) {
    float2 w0 = *(const float2*)(w + 2 * i);
    float2 w1 = *(const float2*)(w + 8 + 2 * i);
    s += b2f(a[i] & 0xffffu) * w0.x + b2f(a[i] >> 16) * w0.y;
    s += b2f(c[i] & 0xffffu) * w1.x + b2f(c[i] >> 16) * w1.y;
  }
  for (int off = 32; off; off >>= 1) s += __shfl_xor(s, off);
  if (lane == 0) ekq[row] = s + cn[n];
}

// ---------------- MFMA GEMM, m97 staging: C = A[M,K] @ Bt[N,K]^T ----------------
// 128x128 tile, 4 waves (2x2), 4x4 mfma_f32_16x16x32_bf16 per wave.
// LDS stride 32 (no pad) — required by global_load_lds lane->dest mapping.
// XCD swizzle when grid is (8,32,*): each XCD owns 4 m-slabs, iterates n fastest
// -> A slab fetched into exactly one XCD L2 (round-robin lin%8 dispatch heuristic).
// OUT==0: bf16 out with optional bias+relu. OUT==1: fp32 partial (split-K).
template<int RELU, int OUT>
__global__ __launch_bounds__(256)
void gemm_bt(const u16* __restrict__ A, const u16* __restrict__ Bt,
             const float* __restrict__ bias, void* __restrict__ Cv,
             int M, int N, int kper, int lda, int ldb, int ksplit,
             long aB, long bB, long biasB, long cB) {
  const int zz = blockIdx.z;
  const int split = zz % ksplit;
  const int batch = zz / ksplit;
  A  += (long)batch * aB + (long)split * kper;
  Bt += (long)batch * bB + (long)split * kper;

  int m_idx = blockIdx.y, n_idx = blockIdx.x;
  if (gridDim.x == 8) {                       // XCD-locality swizzle (256-block plane)
    int f = blockIdx.x + (blockIdx.y << 3);
    int xcd = f & 7, j = f >> 3;
    n_idx = j & 7;
    m_idx = (xcd << 2) | (j >> 3);
  }
  const int m0 = m_idx * 128, n0 = n_idx * 128;

  __shared__ u16 As[128 * 32];
  __shared__ u16 Bs[128 * 32];
  const int tid  = threadIdx.x;
  const int lane = tid & 63, wid = tid >> 6;
  const int wm = (wid >> 1) * 64, wn = (wid & 1) * 64;
  const int lr = lane & 15, quad = lane >> 4;
  const int srow = lane >> 2, scol = (lane & 3) * 8;

  const u16* a0 = A  + (long)(m0 + wid * 32 + srow) * lda + scol;
  const u16* a1 = a0 + (long)16 * lda;
  const u16* b0 = Bt + (long)(n0 + wid * 32 + srow) * ldb + scol;
  const u16* b1 = b0 + (long)16 * ldb;
  u16* la0 = &As[wid * 1024];
  u16* la1 = &As[wid * 1024 + 512];
  u16* lb0 = &Bs[wid * 1024];
  u16* lb1 = &Bs[wid * 1024 + 512];

  f32x4 acc[4][4] = {};

  for (int k0 = 0; k0 < kper; k0 += 32) {
    __syncthreads();
    gl_lds16(a0, la0); gl_lds16(a1, la1);
    gl_lds16(b0, lb0); gl_lds16(b1, lb1);
    a0 += 32; a1 += 32; b0 += 32; b1 += 32;
    __syncthreads();
    bf16x8 af[4], bfr[4];
#pragma unroll
    for (int i = 0; i < 4; ++i)
      af[i]  = *(const bf16x8*)(&As[(wm + i * 16 + lr) * 32 + quad * 8]);
#pragma unroll
    for (int i = 0; i < 4; ++i)
      bfr[i] = *(const bf16x8*)(&Bs[(wn + i * 16 + lr) * 32 + quad * 8]);
#pragma unroll
    for (int mi = 0; mi < 4; ++mi)
#pragma unroll
      for (int ni = 0; ni < 4; ++ni)
        acc[mi][ni] = __builtin_amdgcn_mfma_f32_16x16x32_bf16(af[mi], bfr[ni], acc[mi][ni], 0, 0, 0);
  }

  // epilogue: C/D layout col=lane&15, row=quad*4+reg (verified m89/m91)
  if (OUT == 1) {
    float* C = (float*)Cv + (long)split * ((long)M * N);
#pragma unroll
    for (int mi = 0; mi < 4; ++mi)
#pragma unroll
      for (int ni = 0; ni < 4; ++ni) {
        int col = n0 + wn + ni * 16 + lr;
#pragma unroll
        for (int r = 0; r < 4; ++r) {
          int row = m0 + wm + mi * 16 + quad * 4 + r;
          C[(long)row * N + col] = acc[mi][ni][r];
        }
      }
  } else {
    u16* C = (u16*)Cv + (long)batch * cB;
    const float* bptr = bias ? bias + (long)batch * biasB : nullptr;
#pragma unroll
    for (int mi = 0; mi < 4; ++mi)
#pragma unroll
      for (int ni = 0; ni < 4; ++ni) {
        int col = n0 + wn + ni * 16 + lr;
        float bcol = bptr ? bptr[col] : 0.f;
#pragma unroll
        for (int r = 0; r < 4; ++r) {
          int row = m0 + wm + mi * 16 + quad * 4 + r;
          float v = acc[mi][ni][r] + bcol;
          if (RELU) v = fmaxf(v, 0.f);
          C[(long)row * N + col] = f2b(v);
        }
      }
  }
}

// ---------------- reduce 2 fp32 partials + bias + relu -> bf16 ----------------
__global__ __launch_bounds__(256)
void reduce2_relu(const float* __restrict__ part, const float* __restrict__ bias,
                  u16* __restrict__ outp, int N, long stride) {
  long f4 = ((long)blockIdx.x * 256 + threadIdx.x) * 4;
  float4 v0 = *(const float4*)(part + f4);
  float4 v1 = *(const float4*)(part + stride + f4);
  int col = (int)(f4 % N);
  float4 bb = *(const float4*)(bias + col);
  u16 o[4];
  o[0] = f2b(fmaxf(v0.x + v1.x + bb.x, 0.f));
  o[1] = f2b(fmaxf(v0.y + v1.y + bb.y, 0.f));
  o[2] = f2b(fmaxf(v0.z + v1.z + bb.z, 0.f));
  o[3] = f2b(fmaxf(v0.w + v1.w + bb.w, 0.f));
  *(uint2*)(outp + f4) = *(const uint2*)o;
}

// ------------- res[b,v] = bf16( sum_n ekq[n,b] * (y[n,b,v] + bv[n,v]) ) -------------
__global__ __launch_bounds__(256)
void reduce_res(const u16* __restrict__ y, const float* __restrict__ ekq,
                const float* __restrict__ bvp, u16* __restrict__ res) {
  long f8 = ((long)blockIdx.x * 256 + threadIdx.x) * 8;   // over B_*DV_
  int b = (int)(f8 >> 10);
  int v = (int)(f8 & (DV_ - 1));
  float acc[8] = {};
#pragma unroll
  for (int n = 0; n < NEXP_; ++n) {
    float s = ekq[n * B_ + b];
    uint4 p = *(const uint4*)(y + ((long)(n * B_ + b) * DV_) + v);
    const u32* pi = (const u32*)&p;
    float4 b0 = *(const float4*)(bvp + n * DV_ + v);
    float4 b1 = *(const float4*)(bvp + n * DV_ + v + 4);
    acc[0] += s * (b2f(pi[0] & 0xffffu) + b0.x);
    acc[1] += s * (b2f(pi[0] >> 16)     + b0.y);
    acc[2] += s * (b2f(pi[1] & 0xffffu) + b0.z);
    acc[3] += s * (b2f(pi[1] >> 16)     + b0.w);
    acc[4] += s * (b2f(pi[2] & 0xffffu) + b1.x);
    acc[5] += s * (b2f(pi[2] >> 16)     + b1.y);
    acc[6] += s * (b2f(pi[3] & 0xffffu) + b1.z);
    acc[7] += s * (b2f(pi[3] >> 16)     + b1.w);
  }
  u16 o[8];
#pragma unroll
  for (int i = 0; i < 8; ++i) o[i] = f2b(acc[i]);
  *(uint4*)(res + f8) = *(const uint4*)o;
}

// ---------------- reduce 8 Wl partials + bl, then split/clip/exp ----------------
__global__ __launch_bounds__(256)
void reduce_final(const float* __restrict__ part, const float* __restrict__ bl,
                  float* __restrict__ outp) {
  int flat = blockIdx.x * 256 + threadIdx.x;   // 4096*128
  int c = flat & 127, b = flat >> 7;
  float v = bl[c];
  const long S = (long)B_ * 128;
#pragma unroll
  for (int s = 0; s < 8; ++s) v += part[s * S + flat];
  if (c < 64) {
    outp[b * 64 + c] = v;                                  // mean
  } else {
    int i = b * 64 + (c - 64);
    float ls = fminf(fmaxf(v, -20.f), 2.f);
    outp[262144 + i] = expf(ls);                           // std
    outp[524288 + i] = ls;                                 // log_std
  }
}

extern "C" void kernel_launch(void* const* d_in, const int* in_sizes, int n_in,
                              void* d_out, int out_size, void* d_ws, size_t ws_size,
                              hipStream_t stream) {
  const float* x   = (const float*)d_in[0];
  const int*   task= (const int*)  d_in[1];
  const float* Wb1 = (const float*)d_in[2];
  const float* bb1 = (const float*)d_in[3];
  const float* Wb2 = (const float*)d_in[4];
  const float* bb2 = (const float*)d_in[5];
  const float* We1 = (const float*)d_in[6];
  const float* be1 = (const float*)d_in[7];
  const float* We2 = (const float*)d_in[8];
  const float* be2 = (const float*)d_in[9];
  const float* Wv  = (const float*)d_in[10];
  const float* bv  = (const float*)d_in[11];
  const float* Wk  = (const float*)d_in[12];
  const float* bk  = (const float*)d_in[13];
  const float* Wq  = (const float*)d_in[14];
  const float* bq  = (const float*)d_in[15];
  const float* Wt1 = (const float*)d_in[16];
  const float* bt1 = (const float*)d_in[17];
  const float* Wl  = (const float*)d_in[18];
  const float* bl  = (const float*)d_in[19];
  float* outp = (float*)d_out;

  char* ws = (char*)d_ws;
  size_t off = 0;
  auto alloc = [&](size_t bytes) -> char* {
    char* p = ws + off;
    off += (bytes + 255) & ~(size_t)255;
    return p;
  };

  u16* xb    = (u16*)alloc((size_t)B_ * OBS_ * 2);
  u16* Wb1T  = (u16*)alloc((size_t)DH_ * OBS_ * 2);
  u16* Wb2T  = (u16*)alloc((size_t)DH_ * DH_ * 2);
  u16* We1T  = (u16*)alloc((size_t)NEXP_ * DH_ * DH_ * 2);
  u16* We2T  = (u16*)alloc((size_t)NEXP_ * DH_ * DH_ * 2);
  u16* WvT   = (u16*)alloc((size_t)DV_ * NEXP_ * DH_ * 2);   // [DV][N*DH]
  u16* Wt1T  = (u16*)alloc((size_t)DH_ * DV_ * 2);
  u16* WlT   = (u16*)alloc((size_t)128 * DH_ * 2);
  u16* h1    = (u16*)alloc((size_t)B_ * DH_ * 2);
  u16* h     = (u16*)alloc((size_t)B_ * DH_ * 2);
  u16* e1    = (u16*)alloc((size_t)NEXP_ * B_ * DH_ * 2);    // 64 MB region
  u16* e2    = (u16*)alloc((size_t)NEXP_ * B_ * DH_ * 2);    // 64 MB region
  float* cn  = (float*)alloc(NEXP_ * 4);
  float* wnq = (float*)alloc((size_t)NEXP_ * DH_ * 4);
  float* ekq = (float*)alloc((size_t)NEXP_ * B_ * 4);
  // region reuse (dead by the time they're re-purposed; in-order stream):
  float* partA = (float*)e1;     // h1/h split-K partials (2 x 16 MB fp32)
  u16*   y     = e1;             // y[n][b][v] bf16 (e1 dead after e2 GEMM)
  u16*   res   = h1;             // res [B][DV]  (h1 dead after h GEMM)
  u16*   tt    = h;              // t   [B][DH]  (h dead after e1 GEMM)
  float* partB = (float*)e2;     // Wt1 / Wl split-K partials (e2 dead after y GEMM)

  // prologue: converts + transposes (1 launch), wnq + cn (1 launch)
  prep<<<29312, 256, 0, stream>>>(x, xb, Wb1, Wb1T, Wb2, Wb2T, We1, We1T,
                                  We2, We2T, Wv, WvT, Wt1, Wt1T, Wl, WlT);
  wnq_cn<<<2049, 256, 0, stream>>>(Wq, bq, bk, task, Wk, wnq, cn);

  const long S1 = (long)B_ * DH_;
  // h1 = relu(x@Wb1+bb1)   [split-K 2]
  gemm_bt<0, 1><<<dim3(8, 32, 2), 256, 0, stream>>>(xb, Wb1T, nullptr, partA,
      B_, DH_, 256, OBS_, OBS_, 2, 0, 0, 0, 0);
  reduce2_relu<<<4096, 256, 0, stream>>>(partA, bb1, h1, DH_, S1);
  // h = relu(h1@Wb2+bb2)   [split-K 2]
  gemm_bt<0, 1><<<dim3(8, 32, 2), 256, 0, stream>>>(h1, Wb2T, nullptr, partA,
      B_, DH_, 512, DH_, DH_, 2, 0, 0, 0, 0);
  reduce2_relu<<<4096, 256, 0, stream>>>(partA, bb2, h, DH_, S1);
  // experts (batched over z)
  gemm_bt<1, 0><<<dim3(8, 32, 8), 256, 0, stream>>>(h, We1T, be1, e1,
      B_, DH_, DH_, DH_, DH_, 1, 0, (long)DH_ * DH_, DH_, (long)B_ * DH_);
  gemm_bt<1, 0><<<dim3(8, 32, 8), 256, 0, stream>>>(e1, We2T, be2, e2,
      B_, DH_, DH_, DH_, DH_, 1, (long)B_ * DH_, (long)DH_ * DH_, DH_, (long)B_ * DH_);
  // attention weights (reads e2 once; y GEMM independent of ekq)
  expkq_k<<<(NEXP_ * B_) / 4, 256, 0, stream>>>(e2, wnq, cn, ekq);
  // y[n] = e2_n @ Wv_n  (batched, bf16 out, no bias; per-expert B slice of WvT)
  gemm_bt<0, 0><<<dim3(8, 32, 8), 256, 0, stream>>>(e2, WvT, nullptr, y,
      B_, DV_, DH_, DH_, NEXP_ * DH_, 1, (long)B_ * DH_, DH_, 0, (long)B_ * DV_);
  // res = sum_n ekq * (y + bv)
  reduce_res<<<2048, 256, 0, stream>>>(y, ekq, bv, res);
  // tower: t = relu(res@Wt1+bt1)   [split-K 2]
  gemm_bt<0, 1><<<dim3(8, 32, 2), 256, 0, stream>>>(res, Wt1T, nullptr, partB,
      B_, DH_, 512, DV_, DV_, 2, 0, 0, 0, 0);
  reduce2_relu<<<4096, 256, 0, stream>>>(partB, bt1, tt, DH_, S1);
  // last: out = t@Wl   [split-K 8, N=128]
  gemm_bt<0, 1><<<dim3(1, 32, 8), 256, 0, stream>>>(tt, WlT, nullptr, partB,
      B_, 128, 128, DH_, DH_, 8, 0, 0, 0, 0);
  reduce_final<<<(B_ * 128) / 256, 256, 0, stream>>>(partB, bl, outp);
}

// Round 4
// 492.984 us; speedup vs baseline: 1.5220x; 1.2086x over previous
//
#include <hip/hip_runtime.h>
#include <hip/hip_bf16.h>

typedef unsigned short u16;
typedef unsigned int   u32;
typedef __attribute__((ext_vector_type(4))) float  f32x4;
typedef __attribute__((ext_vector_type(8))) __bf16 bf16x8;

#define B_    4096
#define OBS_  512
#define DH_   1024
#define NEXP_ 8
#define DK_   256
#define DV_   1024

__device__ __forceinline__ float b2f(u32 lo16) {
  return __builtin_bit_cast(float, lo16 << 16);
}
__device__ __forceinline__ u16 f2b(float f) {   // RNE fp32 -> bf16
  u32 u = __builtin_bit_cast(u32, f);
  return (u16)((u + 0x7fffu + ((u >> 16) & 1u)) >> 16);
}
// async global->LDS, 16 B per lane; LDS dest = wave-uniform base + lane*16
__device__ __forceinline__ void gl_lds16(const u16* g, u16* l) {
  __builtin_amdgcn_global_load_lds(
      (__attribute__((address_space(1))) void*)(void*)g,
      (__attribute__((address_space(3))) void*)(void*)l,
      16, 0, 0);
}

// ---------------- merged prologue: fp32->bf16 convert of x + 7 weight transposes ----------------
__device__ __forceinline__ void tconv_body(const float* __restrict__ in,
                                           u16* __restrict__ outp,
                                           int R, int C, int rem, int tid) {
  __shared__ float tile[32][33];
  int gxs = (C == 128) ? 2 : 5;            // log2(C/32)
  int c0 = (rem & ((1 << gxs) - 1)) * 32;
  int r0 = (rem >> gxs) * 32;
  int tx = tid & 31, ty = tid >> 5;        // (32, 8)
#pragma unroll
  for (int i = 0; i < 4; ++i)
    tile[ty + i * 8][tx] = in[(long)(r0 + ty + i * 8) * C + c0 + tx];
  __syncthreads();
#pragma unroll
  for (int i = 0; i < 4; ++i)
    outp[(long)(c0 + ty + i * 8) * R + r0 + tx] = f2b(tile[tx][ty + i * 8]);
}

__global__ __launch_bounds__(256)
void prep(const float* __restrict__ x,  u16* __restrict__ xb,
          const float* __restrict__ Wb1, u16* __restrict__ Wb1T,
          const float* __restrict__ Wb2, u16* __restrict__ Wb2T,
          const float* __restrict__ We1, u16* __restrict__ We1T,
          const float* __restrict__ We2, u16* __restrict__ We2T,
          const float* __restrict__ Wv,  u16* __restrict__ WvT,
          const float* __restrict__ Wt1, u16* __restrict__ Wt1T,
          const float* __restrict__ Wl,  u16* __restrict__ WlT) {
  int tid = threadIdx.x;
  int bid = blockIdx.x;
  if (bid < 2048) {                         // conv x
    long i = ((long)bid * 256 + tid) * 4;
    float4 v = *(const float4*)(x + i);
    u16 o[4] = { f2b(v.x), f2b(v.y), f2b(v.z), f2b(v.w) };
    *(uint2*)(xb + i) = *(const uint2*)o;
    return;
  }
  bid -= 2048;
  if (bid < 512)  { tconv_body(Wb1, Wb1T, 512, 1024, bid, tid); return; }
  bid -= 512;
  if (bid < 1024) { tconv_body(Wb2, Wb2T, 1024, 1024, bid, tid); return; }
  bid -= 1024;
  if (bid < 8192) {
    int z = bid >> 10, rem = bid & 1023;
    tconv_body(We1 + (long)z * DH_ * DH_, We1T + (long)z * DH_ * DH_, 1024, 1024, rem, tid);
    return;
  }
  bid -= 8192;
  if (bid < 8192) {
    int z = bid >> 10, rem = bid & 1023;
    tconv_body(We2 + (long)z * DH_ * DH_, We2T + (long)z * DH_ * DH_, 1024, 1024, rem, tid);
    return;
  }
  bid -= 8192;
  if (bid < 8192) { tconv_body(Wv, WvT, 8192, 1024, bid, tid); return; }
  bid -= 8192;
  if (bid < 1024) { tconv_body(Wt1, Wt1T, 1024, 1024, bid, tid); return; }
  bid -= 1024;
  tconv_body(Wl, WlT, 1024, 128, bid, tid);
}

// ---------------- wnq[n][d] = Wk[n][d][:]·q ; block 2048 computes cn[n] = bk[n]·q ----------------
__global__ __launch_bounds__(256)
void wnq_cn(const float* __restrict__ Wq, const float* __restrict__ bq,
            const float* __restrict__ bk, const int* __restrict__ task,
            const float* __restrict__ Wk, float* __restrict__ wnq,
            float* __restrict__ cn) {
  int t = *task;
  const float* qrow = Wq + (long)(t * 10 + t) * DK_;
  const float* brow = bq + (long)t * DK_;
  int lane = threadIdx.x & 63;
  int bid = blockIdx.x;
  if (bid < 2048) {
    int row = bid * 4 + (threadIdx.x >> 6);   // 0..8191
    const float* wr = Wk + (long)row * DK_;
    float s = 0.f;
#pragma unroll
    for (int i = 0; i < 4; ++i) {
      int j = lane + i * 64;
      s += wr[j] * (qrow[j] + brow[j]);
    }
    for (int off = 32; off; off >>= 1) s += __shfl_xor(s, off);
    if (lane == 0) wnq[row] = s;
  } else {
    int w = threadIdx.x >> 6;
    for (int n = w; n < NEXP_; n += 4) {
      float s = 0.f;
#pragma unroll
      for (int i = 0; i < 4; ++i) {
        int j = lane + i * 64;
        s += bk[n * DK_ + j] * (qrow[j] + brow[j]);
      }
      for (int off = 32; off; off >>= 1) s += __shfl_xor(s, off);
      if (lane == 0) cn[n] = s;
    }
  }
}

// ---------------- expkq[n][b] = e2 row · wnq[n] + c_n  (one wave per row) ----------------
__global__ __launch_bounds__(256)
void expkq_k(const u16* __restrict__ e2, const float* __restrict__ wnq,
             const float* __restrict__ cn, float* __restrict__ ekq) {
  int row  = blockIdx.x * 4 + (threadIdx.x >> 6);   // n*4096 + b
  int n    = row >> 12;
  int lane = threadIdx.x & 63;
  const u16*   er = e2 + (long)row * DH_ + lane * 16;
  const float* w  = wnq + n * DH_ + lane * 16;
  uint4 p0 = *(const uint4*)er;
  uint4 p1 = *(const uint4*)(er + 8);
  float s = 0.f;
  const u32* a = (const u32*)&p0;
  const u32* c = (const u32*)&p1;
#pragma unroll
  for (int i = 0; i < 4; ++i) {
    float2 w0 = *(const float2*)(w + 2 * i);
    float2 w1 = *(const float2*)(w + 8 + 2 * i);
    s += b2f(a[i] & 0xffffu) * w0.x + b2f(a[i] >> 16) * w0.y;
    s += b2f(c[i] & 0xffffu) * w1.x + b2f(c[i] >> 16) * w1.y;
  }
  for (int off = 32; off; off >>= 1) s += __shfl_xor(s, off);
  if (lane == 0) ekq[row] = s + cn[n];
}

// ---------------- MFMA GEMM: C = A[M,K] @ Bt[N,K]^T ----------------
// 128x128 tile, 4 waves (2x2), 4x4 mfma_f32_16x16x32_bf16 per wave, BK=64.
// LDS: stride 64 u16 (128 B) with XOR swizzle (physical colblock = c ^ (row&7)):
//   loader lane L stages (row = L>>3, colblock c = (L&7)^(L>>3)) so the
//   wave-uniform+lane*16 dest of global_load_lds lands data at the swizzled slot;
//   fragment ds_read_b128 then hits every bank exactly 8x (the wave64 floor).
// __launch_bounds__(256,4): cap regs at 128 (64 VGPR + 64 acc) -> 4 blocks/CU.
// OUT==0: bf16 out with optional bias+relu. OUT==1: fp32 partial (split-K).
template<int RELU, int OUT, int LDA, int LDB>
__global__ __launch_bounds__(256, 4)
void gemm_bt(const u16* __restrict__ A, const u16* __restrict__ Bt,
             const float* __restrict__ bias, void* __restrict__ Cv,
             int M, int N, int kper, int ksplit,
             long aB, long bB, long biasB, long cB) {
  const int zz = blockIdx.z;
  const int split = zz % ksplit;
  const int batch = zz / ksplit;
  A  += (long)batch * aB + (long)split * kper;
  Bt += (long)batch * bB + (long)split * kper;

  int m_idx = blockIdx.y, n_idx = blockIdx.x;
  if (gridDim.x == 8) {                       // XCD-locality swizzle (256-block plane)
    int f = blockIdx.x + (blockIdx.y << 3);
    int xcd = f & 7, j = f >> 3;
    n_idx = j & 7;
    m_idx = (xcd << 2) | (j >> 3);
  }
  const int m0 = m_idx * 128, n0 = n_idx * 128;

  __shared__ u16 As[128 * 64];
  __shared__ u16 Bs[128 * 64];
  const int tid  = threadIdx.x;
  const int lane = tid & 63, wid = tid >> 6;
  const int wm = (wid >> 1) * 64, wn = (wid & 1) * 64;
  const int lr = lane & 15, quad = lane >> 4;
  // swizzled stage mapping
  const int srow = lane >> 3;
  const int scol = ((lane & 7) ^ srow) * 8;

  const u16* ap0 = A  + (long)(m0 + wid * 32 +  0 + srow) * LDA + scol;
  const u16* ap1 = A  + (long)(m0 + wid * 32 +  8 + srow) * LDA + scol;
  const u16* ap2 = A  + (long)(m0 + wid * 32 + 16 + srow) * LDA + scol;
  const u16* ap3 = A  + (long)(m0 + wid * 32 + 24 + srow) * LDA + scol;
  const u16* bp0 = Bt + (long)(n0 + wid * 32 +  0 + srow) * LDB + scol;
  const u16* bp1 = Bt + (long)(n0 + wid * 32 +  8 + srow) * LDB + scol;
  const u16* bp2 = Bt + (long)(n0 + wid * 32 + 16 + srow) * LDB + scol;
  const u16* bp3 = Bt + (long)(n0 + wid * 32 + 24 + srow) * LDB + scol;
  u16* la = &As[wid * 2048];
  u16* lb = &Bs[wid * 2048];

  // reader bases (u16 index): row*64 + ((quad+4h)^(lr&7))*8, af[i] at +i*1024
  const int rsw = lr & 7;
  const int aB0 = (wm + lr) * 64 + ((quad    ) ^ rsw) * 8;
  const int aB1 = (wm + lr) * 64 + ((quad + 4) ^ rsw) * 8;
  const int bB0 = (wn + lr) * 64 + ((quad    ) ^ rsw) * 8;
  const int bB1 = (wn + lr) * 64 + ((quad + 4) ^ rsw) * 8;

  f32x4 acc[4][4] = {};

  for (int k0 = 0; k0 < kper; k0 += 64) {
    __syncthreads();
    gl_lds16(ap0 + k0, la);        gl_lds16(ap1 + k0, la + 512);
    gl_lds16(ap2 + k0, la + 1024); gl_lds16(ap3 + k0, la + 1536);
    gl_lds16(bp0 + k0, lb);        gl_lds16(bp1 + k0, lb + 512);
    gl_lds16(bp2 + k0, lb + 1024); gl_lds16(bp3 + k0, lb + 1536);
    __syncthreads();
#pragma unroll
    for (int h = 0; h < 2; ++h) {
      const int ab = h ? aB1 : aB0, bb = h ? bB1 : bB0;
      bf16x8 af[4], bfr[4];
#pragma unroll
      for (int i = 0; i < 4; ++i) af[i]  = *(const bf16x8*)(&As[ab + i * 1024]);
#pragma unroll
      for (int i = 0; i < 4; ++i) bfr[i] = *(const bf16x8*)(&Bs[bb + i * 1024]);
#pragma unroll
      for (int mi = 0; mi < 4; ++mi)
#pragma unroll
        for (int ni = 0; ni < 4; ++ni)
          acc[mi][ni] = __builtin_amdgcn_mfma_f32_16x16x32_bf16(af[mi], bfr[ni], acc[mi][ni], 0, 0, 0);
    }
  }

  // epilogue: C/D layout col=lane&15, row=quad*4+reg (verified m89/m91)
  if (OUT == 1) {
    float* C = (float*)Cv + (long)split * ((long)M * N);
#pragma unroll
    for (int mi = 0; mi < 4; ++mi)
#pragma unroll
      for (int ni = 0; ni < 4; ++ni) {
        int col = n0 + wn + ni * 16 + lr;
#pragma unroll
        for (int r = 0; r < 4; ++r) {
          int row = m0 + wm + mi * 16 + quad * 4 + r;
          C[(long)row * N + col] = acc[mi][ni][r];
        }
      }
  } else {
    u16* C = (u16*)Cv + (long)batch * cB;
    const float* bptr = bias ? bias + (long)batch * biasB : nullptr;
#pragma unroll
    for (int mi = 0; mi < 4; ++mi)
#pragma unroll
      for (int ni = 0; ni < 4; ++ni) {
        int col = n0 + wn + ni * 16 + lr;
        float bcol = bptr ? bptr[col] : 0.f;
#pragma unroll
        for (int r = 0; r < 4; ++r) {
          int row = m0 + wm + mi * 16 + quad * 4 + r;
          float v = acc[mi][ni][r] + bcol;
          if (RELU) v = fmaxf(v, 0.f);
          C[(long)row * N + col] = f2b(v);
        }
      }
  }
}

// ---------------- reduce 2 fp32 partials + bias + relu -> bf16 ----------------
__global__ __launch_bounds__(256)
void reduce2_relu(const float* __restrict__ part, const float* __restrict__ bias,
                  u16* __restrict__ outp, int N, long stride) {
  long f4 = ((long)blockIdx.x * 256 + threadIdx.x) * 4;
  float4 v0 = *(const float4*)(part + f4);
  float4 v1 = *(const float4*)(part + stride + f4);
  int col = (int)(f4 % N);
  float4 bb = *(const float4*)(bias + col);
  u16 o[4];
  o[0] = f2b(fmaxf(v0.x + v1.x + bb.x, 0.f));
  o[1] = f2b(fmaxf(v0.y + v1.y + bb.y, 0.f));
  o[2] = f2b(fmaxf(v0.z + v1.z + bb.z, 0.f));
  o[3] = f2b(fmaxf(v0.w + v1.w + bb.w, 0.f));
  *(uint2*)(outp + f4) = *(const uint2*)o;
}

// ------------- res[b,v] = bf16( sum_n ekq[n,b] * (y[n,b,v] + bv[n,v]) ) -------------
__global__ __launch_bounds__(256)
void reduce_res(const u16* __restrict__ y, const float* __restrict__ ekq,
                const float* __restrict__ bvp, u16* __restrict__ res) {
  long f8 = ((long)blockIdx.x * 256 + threadIdx.x) * 8;   // over B_*DV_
  int b = (int)(f8 >> 10);
  int v = (int)(f8 & (DV_ - 1));
  float acc[8] = {};
#pragma unroll
  for (int n = 0; n < NEXP_; ++n) {
    float s = ekq[n * B_ + b];
    uint4 p = *(const uint4*)(y + ((long)(n * B_ + b) * DV_) + v);
    const u32* pi = (const u32*)&p;
    float4 b0 = *(const float4*)(bvp + n * DV_ + v);
    float4 b1 = *(const float4*)(bvp + n * DV_ + v + 4);
    acc[0] += s * (b2f(pi[0] & 0xffffu) + b0.x);
    acc[1] += s * (b2f(pi[0] >> 16)     + b0.y);
    acc[2] += s * (b2f(pi[1] & 0xffffu) + b0.z);
    acc[3] += s * (b2f(pi[1] >> 16)     + b0.w);
    acc[4] += s * (b2f(pi[2] & 0xffffu) + b1.x);
    acc[5] += s * (b2f(pi[2] >> 16)     + b1.y);
    acc[6] += s * (b2f(pi[3] & 0xffffu) + b1.z);
    acc[7] += s * (b2f(pi[3] >> 16)     + b1.w);
  }
  u16 o[8];
#pragma unroll
  for (int i = 0; i < 8; ++i) o[i] = f2b(acc[i]);
  *(uint4*)(res + f8) = *(const uint4*)o;
}

// ---------------- reduce 8 Wl partials + bl, then split/clip/exp ----------------
__global__ __launch_bounds__(256)
void reduce_final(const float* __restrict__ part, const float* __restrict__ bl,
                  float* __restrict__ outp) {
  int flat = blockIdx.x * 256 + threadIdx.x;   // 4096*128
  int c = flat & 127, b = flat >> 7;
  float v = bl[c];
  const long S = (long)B_ * 128;
#pragma unroll
  for (int s = 0; s < 8; ++s) v += part[s * S + flat];
  if (c < 64) {
    outp[b * 64 + c] = v;                                  // mean
  } else {
    int i = b * 64 + (c - 64);
    float ls = fminf(fmaxf(v, -20.f), 2.f);
    outp[262144 + i] = expf(ls);                           // std
    outp[524288 + i] = ls;                                 // log_std
  }
}

extern "C" void kernel_launch(void* const* d_in, const int* in_sizes, int n_in,
                              void* d_out, int out_size, void* d_ws, size_t ws_size,
                              hipStream_t stream) {
  const float* x   = (const float*)d_in[0];
  const int*   task= (const int*)  d_in[1];
  const float* Wb1 = (const float*)d_in[2];
  const float* bb1 = (const float*)d_in[3];
  const float* Wb2 = (const float*)d_in[4];
  const float* bb2 = (const float*)d_in[5];
  const float* We1 = (const float*)d_in[6];
  const float* be1 = (const float*)d_in[7];
  const float* We2 = (const float*)d_in[8];
  const float* be2 = (const float*)d_in[9];
  const float* Wv  = (const float*)d_in[10];
  const float* bv  = (const float*)d_in[11];
  const float* Wk  = (const float*)d_in[12];
  const float* bk  = (const float*)d_in[13];
  const float* Wq  = (const float*)d_in[14];
  const float* bq  = (const float*)d_in[15];
  const float* Wt1 = (const float*)d_in[16];
  const float* bt1 = (const float*)d_in[17];
  const float* Wl  = (const float*)d_in[18];
  const float* bl  = (const float*)d_in[19];
  float* outp = (float*)d_out;

  char* ws = (char*)d_ws;
  size_t off = 0;
  auto alloc = [&](size_t bytes) -> char* {
    char* p = ws + off;
    off += (bytes + 255) & ~(size_t)255;
    return p;
  };

  u16* xb    = (u16*)alloc((size_t)B_ * OBS_ * 2);
  u16* Wb1T  = (u16*)alloc((size_t)DH_ * OBS_ * 2);
  u16* Wb2T  = (u16*)alloc((size_t)DH_ * DH_ * 2);
  u16* We1T  = (u16*)alloc((size_t)NEXP_ * DH_ * DH_ * 2);
  u16* We2T  = (u16*)alloc((size_t)NEXP_ * DH_ * DH_ * 2);
  u16* WvT   = (u16*)alloc((size_t)DV_ * NEXP_ * DH_ * 2);   // [DV][N*DH]
  u16* Wt1T  = (u16*)alloc((size_t)DH_ * DV_ * 2);
  u16* WlT   = (u16*)alloc((size_t)128 * DH_ * 2);
  u16* h1    = (u16*)alloc((size_t)B_ * DH_ * 2);
  u16* h     = (u16*)alloc((size_t)B_ * DH_ * 2);
  u16* e1    = (u16*)alloc((size_t)NEXP_ * B_ * DH_ * 2);    // 64 MB region
  u16* e2    = (u16*)alloc((size_t)NEXP_ * B_ * DH_ * 2);    // 64 MB region
  float* cn  = (float*)alloc(NEXP_ * 4);
  float* wnq = (float*)alloc((size_t)NEXP_ * DH_ * 4);
  float* ekq = (float*)alloc((size_t)NEXP_ * B_ * 4);
  // region reuse (dead by the time they're re-purposed; in-order stream):
  float* partA = (float*)e1;     // h1/h split-K partials (2 x 16 MB fp32)
  u16*   y     = e1;             // y[n][b][v] bf16 (e1 dead after e2 GEMM)
  u16*   res   = h1;             // res [B][DV]  (h1 dead after h GEMM)
  u16*   tt    = h;              // t   [B][DH]  (h dead after e1 GEMM)
  float* partB = (float*)e2;     // Wt1 / Wl split-K partials (e2 dead after y GEMM)

  // prologue: converts + transposes (1 launch), wnq + cn (1 launch)
  prep<<<29312, 256, 0, stream>>>(x, xb, Wb1, Wb1T, Wb2, Wb2T, We1, We1T,
                                  We2, We2T, Wv, WvT, Wt1, Wt1T, Wl, WlT);
  wnq_cn<<<2049, 256, 0, stream>>>(Wq, bq, bk, task, Wk, wnq, cn);

  const long S1 = (long)B_ * DH_;
  // h1 = relu(x@Wb1+bb1)   [split-K 2]
  gemm_bt<0, 1, OBS_, OBS_><<<dim3(8, 32, 2), 256, 0, stream>>>(xb, Wb1T, nullptr, partA,
      B_, DH_, 256, 2, 0, 0, 0, 0);
  reduce2_relu<<<4096, 256, 0, stream>>>(partA, bb1, h1, DH_, S1);
  // h = relu(h1@Wb2+bb2)   [split-K 2]
  gemm_bt<0, 1, DH_, DH_><<<dim3(8, 32, 2), 256, 0, stream>>>(h1, Wb2T, nullptr, partA,
      B_, DH_, 512, 2, 0, 0, 0, 0);
  reduce2_relu<<<4096, 256, 0, stream>>>(partA, bb2, h, DH_, S1);
  // experts (batched over z)
  gemm_bt<1, 0, DH_, DH_><<<dim3(8, 32, 8), 256, 0, stream>>>(h, We1T, be1, e1,
      B_, DH_, DH_, 1, 0, (long)DH_ * DH_, DH_, (long)B_ * DH_);
  gemm_bt<1, 0, DH_, DH_><<<dim3(8, 32, 8), 256, 0, stream>>>(e1, We2T, be2, e2,
      B_, DH_, DH_, 1, (long)B_ * DH_, (long)DH_ * DH_, DH_, (long)B_ * DH_);
  // attention weights (reads e2 once; y GEMM independent of ekq)
  expkq_k<<<(NEXP_ * B_) / 4, 256, 0, stream>>>(e2, wnq, cn, ekq);
  // y[n] = e2_n @ Wv_n  (batched, bf16 out, no bias; per-expert B slice of WvT)
  gemm_bt<0, 0, DH_, NEXP_ * DH_><<<dim3(8, 32, 8), 256, 0, stream>>>(e2, WvT, nullptr, y,
      B_, DV_, DH_, 1, (long)B_ * DH_, DH_, 0, (long)B_ * DV_);
  // res = sum_n ekq * (y + bv)
  reduce_res<<<2048, 256, 0, stream>>>(y, ekq, bv, res);
  // tower: t = relu(res@Wt1+bt1)   [split-K 2]
  gemm_bt<0, 1, DV_, DV_><<<dim3(8, 32, 2), 256, 0, stream>>>(res, Wt1T, nullptr, partB,
      B_, DH_, 512, 2, 0, 0, 0, 0);
  reduce2_relu<<<4096, 256, 0, stream>>>(partB, bt1, tt, DH_, S1);
  // last: out = t@Wl   [split-K 8, N=128]
  gemm_bt<0, 1, DH_, DH_><<<dim3(1, 32, 8), 256, 0, stream>>>(tt, WlT, nullptr, partB,
      B_, 128, 128, 8, 0, 0, 0, 0);
  reduce_final<<<(B_ * 128) / 256, 256, 0, stream>>>(partB, bl, outp);
}

// Round 5
// 490.162 us; speedup vs baseline: 1.5307x; 1.0058x over previous
//
#include <hip/hip_runtime.h>
#include <hip/hip_bf16.h>

typedef unsigned short u16;
typedef unsigned int   u32;
typedef __attribute__((ext_vector_type(4))) float  f32x4;
typedef __attribute__((ext_vector_type(8))) __bf16 bf16x8;

#define B_    4096
#define OBS_  512
#define DH_   1024
#define NEXP_ 8
#define DK_   256
#define DV_   1024

__device__ __forceinline__ float b2f(u32 lo16) {
  return __builtin_bit_cast(float, lo16 << 16);
}
__device__ __forceinline__ u16 f2b(float f) {   // RNE fp32 -> bf16
  u32 u = __builtin_bit_cast(u32, f);
  return (u16)((u + 0x7fffu + ((u >> 16) & 1u)) >> 16);
}
// async global->LDS, 16 B per lane; LDS dest = wave-uniform base + lane*16
__device__ __forceinline__ void gl_lds16(const u16* g, u16* l) {
  __builtin_amdgcn_global_load_lds(
      (__attribute__((address_space(1))) void*)(void*)g,
      (__attribute__((address_space(3))) void*)(void*)l,
      16, 0, 0);
}

// ---------------- merged prologue ----------------
// conv x + 7 weight transposes + wnq/cn (one launch, block-id segmented)
__device__ __forceinline__ void tconv_body(const float* __restrict__ in,
                                           u16* __restrict__ outp,
                                           int R, int C, int rem, int tid) {
  __shared__ float tile[32][33];
  int gxs = (C == 128) ? 2 : 5;            // log2(C/32)
  int c0 = (rem & ((1 << gxs) - 1)) * 32;
  int r0 = (rem >> gxs) * 32;
  int tx = tid & 31, ty = tid >> 5;        // (32, 8)
#pragma unroll
  for (int i = 0; i < 4; ++i)
    tile[ty + i * 8][tx] = in[(long)(r0 + ty + i * 8) * C + c0 + tx];
  __syncthreads();
#pragma unroll
  for (int i = 0; i < 4; ++i)
    outp[(long)(c0 + ty + i * 8) * R + r0 + tx] = f2b(tile[tx][ty + i * 8]);
}

__global__ __launch_bounds__(256)
void prep(const float* __restrict__ x,  u16* __restrict__ xb,
          const float* __restrict__ Wb1, u16* __restrict__ Wb1T,
          const float* __restrict__ Wb2, u16* __restrict__ Wb2T,
          const float* __restrict__ We1, u16* __restrict__ We1T,
          const float* __restrict__ We2, u16* __restrict__ We2T,
          const float* __restrict__ Wv,  u16* __restrict__ WvT,
          const float* __restrict__ Wt1, u16* __restrict__ Wt1T,
          const float* __restrict__ Wl,  u16* __restrict__ WlT,
          const float* __restrict__ Wq,  const float* __restrict__ bq,
          const float* __restrict__ bk,  const int* __restrict__ task,
          const float* __restrict__ Wk,  float* __restrict__ wnq,
          float* __restrict__ cn) {
  int tid = threadIdx.x;
  int bid = blockIdx.x;
  if (bid < 2048) {                         // conv x
    long i = ((long)bid * 256 + tid) * 4;
    float4 v = *(const float4*)(x + i);
    u16 o[4] = { f2b(v.x), f2b(v.y), f2b(v.z), f2b(v.w) };
    *(uint2*)(xb + i) = *(const uint2*)o;
    return;
  }
  bid -= 2048;
  if (bid < 512)  { tconv_body(Wb1, Wb1T, 512, 1024, bid, tid); return; }
  bid -= 512;
  if (bid < 1024) { tconv_body(Wb2, Wb2T, 1024, 1024, bid, tid); return; }
  bid -= 1024;
  if (bid < 8192) {
    int z = bid >> 10, rem = bid & 1023;
    tconv_body(We1 + (long)z * DH_ * DH_, We1T + (long)z * DH_ * DH_, 1024, 1024, rem, tid);
    return;
  }
  bid -= 8192;
  if (bid < 8192) {
    int z = bid >> 10, rem = bid & 1023;
    tconv_body(We2 + (long)z * DH_ * DH_, We2T + (long)z * DH_ * DH_, 1024, 1024, rem, tid);
    return;
  }
  bid -= 8192;
  if (bid < 8192) { tconv_body(Wv, WvT, 8192, 1024, bid, tid); return; }
  bid -= 8192;
  if (bid < 1024) { tconv_body(Wt1, Wt1T, 1024, 1024, bid, tid); return; }
  bid -= 1024;
  if (bid < 128)  { tconv_body(Wl, WlT, 1024, 128, bid, tid); return; }
  bid -= 128;
  // wnq / cn segment: q[j] = Wq[task][task][j] + bq[task][j]
  int t = *task;
  const float* qrow = Wq + (long)(t * 10 + t) * DK_;
  const float* brow = bq + (long)t * DK_;
  int lane = tid & 63;
  if (bid < 2048) {
    int row = bid * 4 + (tid >> 6);          // 0..8191 = n*DH + d
    const float* wr = Wk + (long)row * DK_;
    float s = 0.f;
#pragma unroll
    for (int i = 0; i < 4; ++i) {
      int j = lane + i * 64;
      s += wr[j] * (qrow[j] + brow[j]);
    }
    for (int off = 32; off; off >>= 1) s += __shfl_xor(s, off);
    if (lane == 0) wnq[row] = s;
  } else {
    int w = tid >> 6;
    for (int n = w; n < NEXP_; n += 4) {
      float s = 0.f;
#pragma unroll
      for (int i = 0; i < 4; ++i) {
        int j = lane + i * 64;
        s += bk[n * DK_ + j] * (qrow[j] + brow[j]);
      }
      for (int off = 32; off; off >>= 1) s += __shfl_xor(s, off);
      if (lane == 0) cn[n] = s;
    }
  }
}

// ---------------- MFMA GEMM, 128x128 tile, 4 waves, BK=64 (small/medium GEMMs) ----------------
// XOR-swizzled LDS (conflict-free, verified r4: SQ_LDS_BANK_CONFLICT=0).
// OUT==0: bf16 out with optional bias+relu. OUT==1: fp32 partial (split-K).
template<int RELU, int OUT, int LDA, int LDB>
__global__ __launch_bounds__(256, 4)
void gemm_bt(const u16* __restrict__ A, const u16* __restrict__ Bt,
             const float* __restrict__ bias, void* __restrict__ Cv,
             int M, int N, int kper, int ksplit,
             long aB, long bB, long biasB, long cB) {
  const int zz = blockIdx.z;
  const int split = zz % ksplit;
  const int batch = zz / ksplit;
  A  += (long)batch * aB + (long)split * kper;
  Bt += (long)batch * bB + (long)split * kper;

  int m_idx = blockIdx.y, n_idx = blockIdx.x;
  if (gridDim.x == 8) {                       // XCD swizzle, 256-block plane
    int f = blockIdx.x + (blockIdx.y << 3);
    int xcd = f & 7, j = f >> 3;
    n_idx = j & 7;
    m_idx = (xcd << 2) | (j >> 3);
  }
  const int m0 = m_idx * 128, n0 = n_idx * 128;

  __shared__ u16 As[128 * 64];
  __shared__ u16 Bs[128 * 64];
  const int tid  = threadIdx.x;
  const int lane = tid & 63, wid = tid >> 6;
  const int wm = (wid >> 1) * 64, wn = (wid & 1) * 64;
  const int lr = lane & 15, quad = lane >> 4;
  const int srow = lane >> 3;
  const int scol = ((lane & 7) ^ srow) * 8;

  const u16* ap0 = A  + (long)(m0 + wid * 32 +  0 + srow) * LDA + scol;
  const u16* ap1 = A  + (long)(m0 + wid * 32 +  8 + srow) * LDA + scol;
  const u16* ap2 = A  + (long)(m0 + wid * 32 + 16 + srow) * LDA + scol;
  const u16* ap3 = A  + (long)(m0 + wid * 32 + 24 + srow) * LDA + scol;
  const u16* bp0 = Bt + (long)(n0 + wid * 32 +  0 + srow) * LDB + scol;
  const u16* bp1 = Bt + (long)(n0 + wid * 32 +  8 + srow) * LDB + scol;
  const u16* bp2 = Bt + (long)(n0 + wid * 32 + 16 + srow) * LDB + scol;
  const u16* bp3 = Bt + (long)(n0 + wid * 32 + 24 + srow) * LDB + scol;
  u16* la = &As[wid * 2048];
  u16* lb = &Bs[wid * 2048];

  const int rsw = lr & 7;
  const int aB0 = (wm + lr) * 64 + ((quad    ) ^ rsw) * 8;
  const int aB1 = (wm + lr) * 64 + ((quad + 4) ^ rsw) * 8;
  const int bB0 = (wn + lr) * 64 + ((quad    ) ^ rsw) * 8;
  const int bB1 = (wn + lr) * 64 + ((quad + 4) ^ rsw) * 8;

  f32x4 acc[4][4] = {};

  for (int k0 = 0; k0 < kper; k0 += 64) {
    __syncthreads();
    gl_lds16(ap0 + k0, la);        gl_lds16(ap1 + k0, la + 512);
    gl_lds16(ap2 + k0, la + 1024); gl_lds16(ap3 + k0, la + 1536);
    gl_lds16(bp0 + k0, lb);        gl_lds16(bp1 + k0, lb + 512);
    gl_lds16(bp2 + k0, lb + 1024); gl_lds16(bp3 + k0, lb + 1536);
    __syncthreads();
#pragma unroll
    for (int h = 0; h < 2; ++h) {
      const int ab = h ? aB1 : aB0, bb = h ? bB1 : bB0;
      bf16x8 af[4], bfr[4];
#pragma unroll
      for (int i = 0; i < 4; ++i) af[i]  = *(const bf16x8*)(&As[ab + i * 1024]);
#pragma unroll
      for (int i = 0; i < 4; ++i) bfr[i] = *(const bf16x8*)(&Bs[bb + i * 1024]);
#pragma unroll
      for (int mi = 0; mi < 4; ++mi)
#pragma unroll
        for (int ni = 0; ni < 4; ++ni)
          acc[mi][ni] = __builtin_amdgcn_mfma_f32_16x16x32_bf16(af[mi], bfr[ni], acc[mi][ni], 0, 0, 0);
    }
  }

  if (OUT == 1) {
    float* C = (float*)Cv + (long)split * ((long)M * N);
#pragma unroll
    for (int mi = 0; mi < 4; ++mi)
#pragma unroll
      for (int ni = 0; ni < 4; ++ni) {
        int col = n0 + wn + ni * 16 + lr;
#pragma unroll
        for (int r = 0; r < 4; ++r) {
          int row = m0 + wm + mi * 16 + quad * 4 + r;
          C[(long)row * N + col] = acc[mi][ni][r];
        }
      }
  } else {
    u16* C = (u16*)Cv + (long)batch * cB;
    const float* bptr = bias ? bias + (long)batch * biasB : nullptr;
#pragma unroll
    for (int mi = 0; mi < 4; ++mi)
#pragma unroll
      for (int ni = 0; ni < 4; ++ni) {
        int col = n0 + wn + ni * 16 + lr;
        float bcol = bptr ? bptr[col] : 0.f;
#pragma unroll
        for (int r = 0; r < 4; ++r) {
          int row = m0 + wm + mi * 16 + quad * 4 + r;
          float v = acc[mi][ni][r] + bcol;
          if (RELU) v = fmaxf(v, 0.f);
          C[(long)row * N + col] = f2b(v);
        }
      }
  }
}

// ---------------- MFMA GEMM, 256x128 tile, 8 waves, BK=64 (big-3 GEMMs) ----------------
// Wave grid 4(m)x2(n) of 64x64. LDS 48 KB -> 2 blocks/CU, 16 waves/CU.
// Halves barriers per MAC vs 128-tile; same XOR swizzle (conflict-free).
// EKQ: epilogue also accumulates ekq[batch][row] += sum_col v*wnq[batch][col]
// via intra-wave shfl reduce + global atomicAdd (ekq zeroed by memset).
template<int RELU, int EKQ, int LDA, int LDB>
__global__ __launch_bounds__(512, 4)
void gemm_bt2(const u16* __restrict__ A, const u16* __restrict__ Bt,
              const float* __restrict__ bias, void* __restrict__ Cv,
              int M, int N, int kper,
              long aB, long bB, long biasB, long cB,
              const float* __restrict__ wnq, float* __restrict__ ekqOut) {
  const int batch = blockIdx.z;
  A  += (long)batch * aB;
  Bt += (long)batch * bB;

  // XCD swizzle for (8,16) plane: xcd = x, each XCD owns 2 m-slabs, n fastest
  int f = blockIdx.x + (blockIdx.y << 3);
  int xcd = f & 7, j = f >> 3;
  const int n_idx = j & 7;
  const int m_idx = (xcd << 1) | (j >> 3);
  const int m0 = m_idx * 256, n0 = n_idx * 128;

  __shared__ u16 As[256 * 64];
  __shared__ u16 Bs[128 * 64];
  const int tid  = threadIdx.x;
  const int lane = tid & 63, wid = tid >> 6;          // 8 waves
  const int wm = (wid >> 1) * 64, wn = (wid & 1) * 64;
  const int lr = lane & 15, quad = lane >> 4;
  const int srow = lane >> 3;
  const int scol = ((lane & 7) ^ srow) * 8;

  // staging: wave w covers A rows [w*32, w*32+32), B rows [w*16, w*16+16)
  const u16* ap0 = A  + (long)(m0 + wid * 32 +  0 + srow) * LDA + scol;
  const u16* ap1 = A  + (long)(m0 + wid * 32 +  8 + srow) * LDA + scol;
  const u16* ap2 = A  + (long)(m0 + wid * 32 + 16 + srow) * LDA + scol;
  const u16* ap3 = A  + (long)(m0 + wid * 32 + 24 + srow) * LDA + scol;
  const u16* bp0 = Bt + (long)(n0 + wid * 16 +  0 + srow) * LDB + scol;
  const u16* bp1 = Bt + (long)(n0 + wid * 16 +  8 + srow) * LDB + scol;
  u16* la = &As[wid * 2048];
  u16* lb = &Bs[wid * 1024];

  const int rsw = lr & 7;
  const int aB0 = (wm + lr) * 64 + ((quad    ) ^ rsw) * 8;
  const int aB1 = (wm + lr) * 64 + ((quad + 4) ^ rsw) * 8;
  const int bB0 = (wn + lr) * 64 + ((quad    ) ^ rsw) * 8;
  const int bB1 = (wn + lr) * 64 + ((quad + 4) ^ rsw) * 8;

  f32x4 acc[4][4] = {};

  for (int k0 = 0; k0 < kper; k0 += 64) {
    __syncthreads();
    gl_lds16(ap0 + k0, la);        gl_lds16(ap1 + k0, la + 512);
    gl_lds16(ap2 + k0, la + 1024); gl_lds16(ap3 + k0, la + 1536);
    gl_lds16(bp0 + k0, lb);        gl_lds16(bp1 + k0, lb + 512);
    __syncthreads();
#pragma unroll
    for (int h = 0; h < 2; ++h) {
      const int ab = h ? aB1 : aB0, bb = h ? bB1 : bB0;
      bf16x8 af[4], bfr[4];
#pragma unroll
      for (int i = 0; i < 4; ++i) af[i]  = *(const bf16x8*)(&As[ab + i * 1024]);
#pragma unroll
      for (int i = 0; i < 4; ++i) bfr[i] = *(const bf16x8*)(&Bs[bb + i * 1024]);
#pragma unroll
      for (int mi = 0; mi < 4; ++mi)
#pragma unroll
        for (int ni = 0; ni < 4; ++ni)
          acc[mi][ni] = __builtin_amdgcn_mfma_f32_16x16x32_bf16(af[mi], bfr[ni], acc[mi][ni], 0, 0, 0);
    }
  }

  // epilogue: C/D layout col=lane&15, row=quad*4+reg
  u16* C = (u16*)Cv + (long)batch * cB;
  const float* bptr = bias ? bias + (long)batch * biasB : nullptr;
#pragma unroll
  for (int mi = 0; mi < 4; ++mi) {
    float psum[4] = {0.f, 0.f, 0.f, 0.f};
#pragma unroll
    for (int ni = 0; ni < 4; ++ni) {
      int col = n0 + wn + ni * 16 + lr;
      float bcol = bptr ? bptr[col] : 0.f;
      float wq = EKQ ? wnq[(long)batch * N + col] : 0.f;
#pragma unroll
      for (int r = 0; r < 4; ++r) {
        int row = m0 + wm + mi * 16 + quad * 4 + r;
        float v = acc[mi][ni][r] + bcol;
        if (RELU) v = fmaxf(v, 0.f);
        C[(long)row * N + col] = f2b(v);
        if (EKQ) psum[r] += v * wq;
      }
    }
    if (EKQ) {
#pragma unroll
      for (int r = 0; r < 4; ++r) {
        float s = psum[r];
        s += __shfl_xor(s, 1); s += __shfl_xor(s, 2);
        s += __shfl_xor(s, 4); s += __shfl_xor(s, 8);
        if (lr == 0)
          atomicAdd(ekqOut + (long)batch * M + (m0 + wm + mi * 16 + quad * 4 + r), s);
      }
    }
  }
}

// ---------------- reduce 2 fp32 partials + bias + relu -> bf16 ----------------
__global__ __launch_bounds__(256)
void reduce2_relu(const float* __restrict__ part, const float* __restrict__ bias,
                  u16* __restrict__ outp, int N, long stride) {
  long f4 = ((long)blockIdx.x * 256 + threadIdx.x) * 4;
  float4 v0 = *(const float4*)(part + f4);
  float4 v1 = *(const float4*)(part + stride + f4);
  int col = (int)(f4 % N);
  float4 bb = *(const float4*)(bias + col);
  u16 o[4];
  o[0] = f2b(fmaxf(v0.x + v1.x + bb.x, 0.f));
  o[1] = f2b(fmaxf(v0.y + v1.y + bb.y, 0.f));
  o[2] = f2b(fmaxf(v0.z + v1.z + bb.z, 0.f));
  o[3] = f2b(fmaxf(v0.w + v1.w + bb.w, 0.f));
  *(uint2*)(outp + f4) = *(const uint2*)o;
}

// ------------- res[b,v] = bf16( sum_n (ekq[n,b]+cn[n]) * (y[n,b,v] + bv[n,v]) ) -------------
__global__ __launch_bounds__(256)
void reduce_res(const u16* __restrict__ y, const float* __restrict__ ekq,
                const float* __restrict__ cn, const float* __restrict__ bvp,
                u16* __restrict__ res) {
  long f8 = ((long)blockIdx.x * 256 + threadIdx.x) * 8;   // over B_*DV_
  int b = (int)(f8 >> 10);
  int v = (int)(f8 & (DV_ - 1));
  float acc[8] = {};
#pragma unroll
  for (int n = 0; n < NEXP_; ++n) {
    float s = ekq[n * B_ + b] + cn[n];
    uint4 p = *(const uint4*)(y + ((long)(n * B_ + b) * DV_) + v);
    const u32* pi = (const u32*)&p;
    float4 b0 = *(const float4*)(bvp + n * DV_ + v);
    float4 b1 = *(const float4*)(bvp + n * DV_ + v + 4);
    acc[0] += s * (b2f(pi[0] & 0xffffu) + b0.x);
    acc[1] += s * (b2f(pi[0] >> 16)     + b0.y);
    acc[2] += s * (b2f(pi[1] & 0xffffu) + b0.z);
    acc[3] += s * (b2f(pi[1] >> 16)     + b0.w);
    acc[4] += s * (b2f(pi[2] & 0xffffu) + b1.x);
    acc[5] += s * (b2f(pi[2] >> 16)     + b1.y);
    acc[6] += s * (b2f(pi[3] & 0xffffu) + b1.z);
    acc[7] += s * (b2f(pi[3] >> 16)     + b1.w);
  }
  u16 o[8];
#pragma unroll
  for (int i = 0; i < 8; ++i) o[i] = f2b(acc[i]);
  *(uint4*)(res + f8) = *(const uint4*)o;
}

// ---------------- reduce 8 Wl partials + bl, then split/clip/exp ----------------
__global__ __launch_bounds__(256)
void reduce_final(const float* __restrict__ part, const float* __restrict__ bl,
                  float* __restrict__ outp) {
  int flat = blockIdx.x * 256 + threadIdx.x;   // 4096*128
  int c = flat & 127, b = flat >> 7;
  float v = bl[c];
  const long S = (long)B_ * 128;
#pragma unroll
  for (int s = 0; s < 8; ++s) v += part[s * S + flat];
  if (c < 64) {
    outp[b * 64 + c] = v;                                  // mean
  } else {
    int i = b * 64 + (c - 64);
    float ls = fminf(fmaxf(v, -20.f), 2.f);
    outp[262144 + i] = expf(ls);                           // std
    outp[524288 + i] = ls;                                 // log_std
  }
}

extern "C" void kernel_launch(void* const* d_in, const int* in_sizes, int n_in,
                              void* d_out, int out_size, void* d_ws, size_t ws_size,
                              hipStream_t stream) {
  const float* x   = (const float*)d_in[0];
  const int*   task= (const int*)  d_in[1];
  const float* Wb1 = (const float*)d_in[2];
  const float* bb1 = (const float*)d_in[3];
  const float* Wb2 = (const float*)d_in[4];
  const float* bb2 = (const float*)d_in[5];
  const float* We1 = (const float*)d_in[6];
  const float* be1 = (const float*)d_in[7];
  const float* We2 = (const float*)d_in[8];
  const float* be2 = (const float*)d_in[9];
  const float* Wv  = (const float*)d_in[10];
  const float* bv  = (const float*)d_in[11];
  const float* Wk  = (const float*)d_in[12];
  const float* bk  = (const float*)d_in[13];
  const float* Wq  = (const float*)d_in[14];
  const float* bq  = (const float*)d_in[15];
  const float* Wt1 = (const float*)d_in[16];
  const float* bt1 = (const float*)d_in[17];
  const float* Wl  = (const float*)d_in[18];
  const float* bl  = (const float*)d_in[19];
  float* outp = (float*)d_out;

  char* ws = (char*)d_ws;
  size_t off = 0;
  auto alloc = [&](size_t bytes) -> char* {
    char* p = ws + off;
    off += (bytes + 255) & ~(size_t)255;
    return p;
  };

  u16* xb    = (u16*)alloc((size_t)B_ * OBS_ * 2);
  u16* Wb1T  = (u16*)alloc((size_t)DH_ * OBS_ * 2);
  u16* Wb2T  = (u16*)alloc((size_t)DH_ * DH_ * 2);
  u16* We1T  = (u16*)alloc((size_t)NEXP_ * DH_ * DH_ * 2);
  u16* We2T  = (u16*)alloc((size_t)NEXP_ * DH_ * DH_ * 2);
  u16* WvT   = (u16*)alloc((size_t)DV_ * NEXP_ * DH_ * 2);   // [DV][N*DH]
  u16* Wt1T  = (u16*)alloc((size_t)DH_ * DV_ * 2);
  u16* WlT   = (u16*)alloc((size_t)128 * DH_ * 2);
  u16* h1    = (u16*)alloc((size_t)B_ * DH_ * 2);
  u16* h     = (u16*)alloc((size_t)B_ * DH_ * 2);
  u16* e1    = (u16*)alloc((size_t)NEXP_ * B_ * DH_ * 2);    // 64 MB region
  u16* e2    = (u16*)alloc((size_t)NEXP_ * B_ * DH_ * 2);    // 64 MB region
  float* cn  = (float*)alloc(NEXP_ * 4);
  float* wnq = (float*)alloc((size_t)NEXP_ * DH_ * 4);
  float* ekq = (float*)alloc((size_t)NEXP_ * B_ * 4);
  // region reuse (dead by the time they're re-purposed; in-order stream):
  float* partA = (float*)e1;     // h1/h split-K partials (2 x 16 MB fp32)
  u16*   y     = e1;             // y[n][b][v] bf16 (e1 dead after e2 GEMM)
  u16*   res   = h1;             // res [B][DV]  (h1 dead after h GEMM)
  u16*   tt    = h;              // t   [B][DH]  (h dead after e1 GEMM)
  float* partB = (float*)e2;     // Wt1 / Wl split-K partials (e2 dead after y GEMM)

  // zero ekq accumulator (atomics target); memset node is graph-capture safe
  hipMemsetAsync(ekq, 0, (size_t)NEXP_ * B_ * 4, stream);
  // prologue: converts + transposes + wnq/cn, single launch
  prep<<<31361, 256, 0, stream>>>(x, xb, Wb1, Wb1T, Wb2, Wb2T, We1, We1T,
                                  We2, We2T, Wv, WvT, Wt1, Wt1T, Wl, WlT,
                                  Wq, bq, bk, task, Wk, wnq, cn);

  const long S1 = (long)B_ * DH_;
  // h1 = relu(x@Wb1+bb1)   [split-K 2]
  gemm_bt<0, 1, OBS_, OBS_><<<dim3(8, 32, 2), 256, 0, stream>>>(xb, Wb1T, nullptr, partA,
      B_, DH_, 256, 2, 0, 0, 0, 0);
  reduce2_relu<<<4096, 256, 0, stream>>>(partA, bb1, h1, DH_, S1);
  // h = relu(h1@Wb2+bb2)   [split-K 2]
  gemm_bt<0, 1, DH_, DH_><<<dim3(8, 32, 2), 256, 0, stream>>>(h1, Wb2T, nullptr, partA,
      B_, DH_, 512, 2, 0, 0, 0, 0);
  reduce2_relu<<<4096, 256, 0, stream>>>(partA, bb2, h, DH_, S1);
  // e1 = relu(h@We1+be1)   (256x128 tile, batched over experts)
  gemm_bt2<1, 0, DH_, DH_><<<dim3(8, 16, 8), 512, 0, stream>>>(h, We1T, be1, e1,
      B_, DH_, DH_, 0, (long)DH_ * DH_, DH_, (long)B_ * DH_, nullptr, nullptr);
  // e2 = relu(e1@We2+be2), epilogue also accumulates ekq via atomics
  gemm_bt2<1, 1, DH_, DH_><<<dim3(8, 16, 8), 512, 0, stream>>>(e1, We2T, be2, e2,
      B_, DH_, DH_, (long)B_ * DH_, (long)DH_ * DH_, DH_, (long)B_ * DH_, wnq, ekq);
  // y[n] = e2_n @ Wv_n  (per-expert B slice of WvT)
  gemm_bt2<0, 0, DH_, NEXP_ * DH_><<<dim3(8, 16, 8), 512, 0, stream>>>(e2, WvT, nullptr, y,
      B_, DV_, DH_, (long)B_ * DH_, DH_, 0, (long)B_ * DV_, nullptr, nullptr);
  // res = sum_n (ekq+cn) * (y + bv)
  reduce_res<<<2048, 256, 0, stream>>>(y, ekq, cn, bv, res);
  // tower: t = relu(res@Wt1+bt1)   [split-K 2]
  gemm_bt<0, 1, DV_, DV_><<<dim3(8, 32, 2), 256, 0, stream>>>(res, Wt1T, nullptr, partB,
      B_, DH_, 512, 2, 0, 0, 0, 0);
  reduce2_relu<<<4096, 256, 0, stream>>>(partB, bt1, tt, DH_, S1);
  // last: out = t@Wl   [split-K 8, N=128]
  gemm_bt<0, 1, DH_, DH_><<<dim3(1, 32, 8), 256, 0, stream>>>(tt, WlT, nullptr, partB,
      B_, 128, 128, 8, 0, 0, 0, 0);
  reduce_final<<<(B_ * 128) / 256, 256, 0, stream>>>(partB, bl, outp);
}